// Round 13
// baseline (222.625 us; speedup 1.0000x reference)
//
#include <hip/hip_runtime.h>
#include <hip/hip_bf16.h>

// LinearCDE: y_{t+1} = y_t + A_t y_t + b_t, A_t = reshape(vf_A_W @ u_t, HxH),
// u_t = [1, X[:,t+1]] * DT.  CLIP=1e11 => tanh is identity to ~1e-10 rel.
//
// Round-13: chunk_a was LDS-throughput-bound (320KB/step/block, 4x read
// redundancy). Changes: (1) 8 waves x 64x32 tiles (512 thr) -> ~200KB/step,
// A stays in LDS (no reg-array spill risk). (2) CHUNK 16->8 -> 256 chunk_a
// blocks (full GPU) with NO duplicate fetch (r12's column-split doubled
// fetch; this doesn't). (3) GEMM out-copy simplified (As row = m').
#define DT 0.025f
#define Bz 8
#define Sz 512
#define Dz 64
#define Hz 128
#define NT 511            // S-1 steps
#define OO (Hz * Hz)      // 16384
#define KK (Dz + 1)       // 65
#define CHUNK 8

using short8 = __attribute__((ext_vector_type(8))) short;
using f32x4  = __attribute__((ext_vector_type(4))) float;
using u16x8  = __attribute__((ext_vector_type(8))) unsigned short;
using u16x4  = __attribute__((ext_vector_type(4))) unsigned short;

__device__ __forceinline__ float bf2f(unsigned short u) {
    union { unsigned int i; float f; } v;
    v.i = ((unsigned int)u) << 16;
    return v.f;
}
__device__ __forceinline__ unsigned short f2bf(float f) {
    union { float f; unsigned int i; } v;
    v.f = f;
    unsigned int u = v.i;
    return (unsigned short)((u + 0x7FFFu + ((u >> 16) & 1u)) >> 16);  // RNE
}
// packed f32x2 -> bf16x2 (RNE), gfx950 hw cvt
__device__ __forceinline__ unsigned int cvt_pk_bf16(float lo, float hi) {
    unsigned int r;
    asm("v_cvt_pk_bf16_f32 %0, %1, %2" : "=v"(r) : "v"(lo), "v"(hi));
    return r;
}

// async 16B global -> LDS (dest: wave-uniform base + lane*16)
__device__ __forceinline__ void dma16(const void* g, void* s) {
    __builtin_amdgcn_global_load_lds(
        (const __attribute__((address_space(1))) unsigned int*)g,
        (__attribute__((address_space(3))) unsigned int*)s, 16, 0, 0);
}

// -------- split vf_A_W: Wh/Wl bf16 [o][64] (d=1..64), WA0d = DT*col0 --------
__global__ __launch_bounds__(256) void k_wsplit(const float* __restrict__ WA,
                                                unsigned short* __restrict__ Wh,
                                                unsigned short* __restrict__ Wl,
                                                float* __restrict__ WA0d) {
    int idx = blockIdx.x * 256 + threadIdx.x;   // 512 blocks: 16384 o x 8 units
    int o = idx >> 3, u = idx & 7;
    const float* wr = WA + (size_t)o * KK + 1 + u * 8;
    u16x8 h = {}, lo = {};
#pragma unroll
    for (int j = 0; j < 8; ++j) {
        float v = wr[j];
        unsigned short hh = f2bf(v);
        h[j] = hh;
        lo[j] = f2bf(v - bf2f(hh));
    }
    *(u16x8*)(Wh + (size_t)o * 64 + u * 8) = h;
    *(u16x8*)(Wl + (size_t)o * 64 + u * 8) = lo;
    if (u == 0) WA0d[o] = DT * WA[(size_t)o * KK];
}

// -------- per-slice u: Xh bf16 [m'][64], m' = b*Lpad+lt, zero-padded --------
__global__ __launch_bounds__(256) void k_prep(const float* __restrict__ X,
                                              unsigned short* __restrict__ Xh,
                                              int t0, int Lsteps, int Lpad) {
    int idx = blockIdx.x * 256 + threadIdx.x;
    int m = idx >> 3, u = idx & 7;
    int b = m / Lpad, lt = m - b * Lpad;
    u16x8 h = {};
    if (lt < Lsteps) {
        const float* xr = X + ((size_t)b * Sz + t0 + lt + 1) * Dz + u * 8;
#pragma unroll
        for (int j = 0; j < 8; ++j) h[j] = f2bf(xr[j] * DT);
    }
    *(u16x8*)(Xh + (size_t)m * 64 + u * 8) = h;
}

// -------- y0 = X[:,0] @ init_W^T + init_b --------
__global__ __launch_bounds__(256) void k_y0(const float* __restrict__ X,
                                            const float* __restrict__ W,
                                            const float* __restrict__ bias,
                                            float* __restrict__ out) {
    int idx = blockIdx.x * 256 + threadIdx.x;
    int b = idx >> 7, h = idx & 127;
    const float* xr = X + (size_t)b * Sz * Dz;
    const float* wr = W + (size_t)h * Dz;
    float acc = bias[h];
    for (int d = 0; d < Dz; ++d) acc += xr[d] * wr[d];
    out[(size_t)b * Sz * Hz + h] = acc;
}

// -------- Bs[bt,h] --------
__global__ __launch_bounds__(256) void k_bs(const float* __restrict__ X,
                                            const float* __restrict__ WB,
                                            float* __restrict__ Bs) {
    int idx = blockIdx.x * 256 + threadIdx.x;
    int bt = idx >> 7, h = idx & 127;
    int b = bt / NT, t = bt - b * NT;
    const float* xr = X + ((size_t)b * Sz + t + 1) * Dz;
    const float* wr = WB + (size_t)h * KK;
    float acc = wr[0];
    for (int k = 0; k < Dz; ++k) acc += xr[k] * wr[1 + k];
    Bs[(size_t)bt * Hz + h] = acc * DT;
}

// -------- As GEMM via MFMA, 2-term split, step-major output --------
// block 256 thr (4 waves 2x2), tile 128 m' x 128 o, K=64.
// As[m'][o] = bf16( xh*(Wh+Wl) + DT*WA[o][0] )
__global__ __launch_bounds__(256, 3) void k_gemm_mfma(
    const unsigned short* __restrict__ Xh,
    const unsigned short* __restrict__ Wh, const unsigned short* __restrict__ Wl,
    const float* __restrict__ WA0d, unsigned short* __restrict__ As) {
    const int tid = threadIdx.x;
    const int w = tid >> 6, l = tid & 63;
    const int lr = l & 15, lg = l >> 4;
    const int wbt = w >> 1, wo = w & 1;
    const int o0 = blockIdx.x * 128;
    const int bt0 = blockIdx.y * 128;

    __shared__ __align__(16) unsigned short L[3 * 8192];  // Xh|Wh|Wl 128x64

#pragma unroll
    for (int q = 0; q < 4; ++q) {
        int seg = w * 4 + q;                 // 0..15 per buffer
        int du = seg * 64 + l;               // 0..1023 16B-units
        int row = du >> 3;
        int su = (du & ~7) | ((du & 7) ^ (row & 7));
        dma16(Xh + (size_t)bt0 * 64 + su * 8, &L[0 * 8192 + seg * 512]);
        dma16(Wh + (size_t)o0 * 64 + su * 8, &L[1 * 8192 + seg * 512]);
        dma16(Wl + (size_t)o0 * 64 + su * 8, &L[2 * 8192 + seg * 512]);
    }
    __syncthreads();   // implicit vmcnt(0): staging done

    f32x4 acc[4][4] = {};   // [oti][bti]
    const unsigned short* Xh_l = &L[0];
    const unsigned short* Wh_l = &L[8192];
    const unsigned short* Wl_l = &L[16384];

#pragma unroll
    for (int kk = 0; kk < 2; ++kk) {
        short8 xh[4], wh[4], wl[4];
#pragma unroll
        for (int t = 0; t < 4; ++t) {
            int btr = wbt * 64 + t * 16 + lr;
            int orr = wo * 64 + t * 16 + lr;
            int ux = (kk * 4 + lg) ^ (btr & 7);
            int uw = (kk * 4 + lg) ^ (orr & 7);
            xh[t] = *(const short8*)&Xh_l[btr * 64 + ux * 8];
            wh[t] = *(const short8*)&Wh_l[orr * 64 + uw * 8];
            wl[t] = *(const short8*)&Wl_l[orr * 64 + uw * 8];
        }
#pragma unroll
        for (int ot = 0; ot < 4; ++ot)
#pragma unroll
            for (int bt = 0; bt < 4; ++bt) {
                acc[ot][bt] = __builtin_amdgcn_mfma_f32_16x16x32_bf16(
                    wh[ot], xh[bt], acc[ot][bt], 0, 0, 0);
                acc[ot][bt] = __builtin_amdgcn_mfma_f32_16x16x32_bf16(
                    wl[ot], xh[bt], acc[ot][bt], 0, 0, 0);
            }
    }

    __syncthreads();                 // frag reads done; reuse L[0:16K u16] as T
    // T: 128 rows (m'_local) x 128 cols (o_local), 8B-unit XOR swizzle
    unsigned short* T = &L[0];
#pragma unroll
    for (int ot = 0; ot < 4; ++ot) {
        int obase = wo * 64 + ot * 16 + lg * 4;
        float4 wa = *(const float4*)&WA0d[o0 + obase];
#pragma unroll
        for (int bt = 0; bt < 4; ++bt) {
            int btl = wbt * 64 + bt * 16 + lr;
            u16x4 pk;
            pk[0] = f2bf(acc[ot][bt][0] + wa.x);
            pk[1] = f2bf(acc[ot][bt][1] + wa.y);
            pk[2] = f2bf(acc[ot][bt][2] + wa.z);
            pk[3] = f2bf(acc[ot][bt][3] + wa.w);
            int up = (obase >> 2) ^ ((btl & 15) << 1);
            *(u16x4*)&T[btl * 128 + up * 4] = pk;
        }
    }
    __syncthreads();
    // out-copy: per instruction, 16 lanes fully cover each 256B segment;
    // As row index = m' (global) directly.
    const int lane16 = tid & 15;
    const int segb = tid >> 4;           // 0..15
#pragma unroll
    for (int it = 0; it < 8; ++it) {
        int seg = it * 16 + segb;        // m'_local 0..127
        int up = (lane16 * 2) ^ ((seg & 15) << 1);
        u16x8 val = *(const u16x8*)&T[seg * 128 + up * 4];
        *(u16x8*)(As + (size_t)(bt0 + seg) * OO + o0 + lane16 * 8) = val;
    }
}

// -------- stage helper for chunk_a: 32KB contiguous, pre-swizzled source ----
// 512 threads: each lane issues 4 dma16 (seg = w*4+q, 32 segs x 1KB).
__device__ __forceinline__ void stage_a(const unsigned short* Astep,
                                        unsigned short* dstBuf, int w, int l) {
#pragma unroll
    for (int q = 0; q < 4; ++q) {
        int seg = w * 4 + q;                 // 0..31
        int du = seg * 64 + l;               // 0..2047 16B-units
        int row = du >> 4, cu = du & 15;
        int su = (du & ~15) | (cu ^ (row & 7));
        dma16(Astep + (size_t)su * 8, &dstBuf[seg * 512]);
    }
}

// -------- stage a: per-chunk Delta (128x128) and v via MFMA --------
// grid (NCs, Bz); 512 thr = 8 waves (wr = w>>2 in {0,1}: 64-row strip;
// wc = w&3: 32-col strip). A in LDS ring-3 (vmcnt(4)); Pt single-buffer,
// 2 barriers/step (proven schedule). v by wc==0 waves reusing af frags.
__global__ __launch_bounds__(512, 1) void k_chunk_a(
    const unsigned short* __restrict__ As, const float* __restrict__ Bs,
    float* __restrict__ Dm, float* __restrict__ Vv,
    int t0, int Lsteps, int NCs) {
    const int cs = blockIdx.x, b = blockIdx.y;
    const int tid = threadIdx.x;
    const int w = tid >> 6, l = tid & 63;
    const int lr = l & 15, lg = l >> 4;
    const int wr = w >> 2, wc = w & 3;
    int Lc = Lsteps - cs * CHUNK; if (Lc > CHUNK) Lc = CHUNK;

    __shared__ __align__(16) unsigned short AbufF[3 * OO];   // 96 KB ring
    __shared__ __align__(16) unsigned short Pt[129 * Hz];    // 33 KB (P^T ; v)
    __shared__ __align__(16) float BsL[CHUNK][Hz];           // 4 KB

    const unsigned short* AsC = As + (size_t)(b * NCs + cs) * CHUNK * OO;

    stage_a(AsC, &AbufF[0], w, l);                    // buf 0 = step 0
    if (Lc > 1) stage_a(AsC + OO, &AbufF[OO], w, l);  // buf 1 = step 1

    // Pt = [I ; v=0] (swizzled rows)
    for (int idx = tid; idx < 129 * Hz; idx += 512) {
        int row = idx >> 7, col = idx & 127;
        unsigned short val = (row < Hz && row == col) ? (unsigned short)0x3F80
                                                      : (unsigned short)0;
        int unit = (col >> 3) ^ (row & 7);
        Pt[(row << 7) | (unit << 3) | (col & 7)] = val;
    }
    const int t0c = t0 + cs * CHUNK;
    for (int idx = tid; idx < Lc * Hz; idx += 512) {
        int row = idx >> 7, col = idx & 127;
        BsL[row][col] = Bs[((size_t)b * NT + t0c + row) * Hz + col];
    }

    // identity: acc[tix][tjx][r] needs +1 iff r == rd[tix][tjx]
    int rd[4][2];
#pragma unroll
    for (int tix = 0; tix < 4; ++tix)
#pragma unroll
        for (int tjx = 0; tjx < 2; ++tjx)
            rd[tix][tjx] = (32 * wc + 16 * tjx + lr) -
                           (64 * wr + 16 * tix + 4 * lg);

    f32x4 acc[4][2] = {};
    f32x4 vacc[4] = {};
    int b0 = 0, b1 = 1, b2 = 2;
    const int kxor = lr & 7;

    for (int k = 0; k < Lc; ++k) {
        // buf[b0] (issued at k-2) complete; next stage's 4 loads stay in flight
        if (k + 1 < Lc) {
            asm volatile("s_waitcnt vmcnt(4) lgkmcnt(0)" ::: "memory");
        } else {
            asm volatile("s_waitcnt vmcnt(0) lgkmcnt(0)" ::: "memory");
        }
        __builtin_amdgcn_s_barrier();
        asm volatile("" ::: "memory");

        if (k + 2 < Lc)
            stage_a(AsC + (size_t)(k + 2) * OO, &AbufF[b2 * OO], w, l);

        const unsigned short* Ac = &AbufF[b0 * OO];
#pragma unroll
        for (int kt = 0; kt < 4; ++kt) {
            const int uoff = ((kt * 4 + lg) ^ kxor) << 3;
            short8 af[4];
#pragma unroll
            for (int tix = 0; tix < 4; ++tix)
                af[tix] = *(const short8*)
                    &Ac[((64 * wr + 16 * tix + lr) << 7) | uoff];
            short8 bf0 = *(const short8*)&Pt[((32 * wc + lr) << 7) | uoff];
            short8 bf1 = *(const short8*)&Pt[((32 * wc + 16 + lr) << 7) | uoff];
#pragma unroll
            for (int tix = 0; tix < 4; ++tix) {
                acc[tix][0] = __builtin_amdgcn_mfma_f32_16x16x32_bf16(
                    af[tix], bf0, acc[tix][0], 0, 0, 0);
                acc[tix][1] = __builtin_amdgcn_mfma_f32_16x16x32_bf16(
                    af[tix], bf1, acc[tix][1], 0, 0, 0);
            }
            if (wc == 0) {
                short8 vf = *(const short8*)&Pt[(128 << 7) |
                                                ((kt * 4 + lg) << 3)];
#pragma unroll
                for (int tix = 0; tix < 4; ++tix)
                    vacc[tix] = __builtin_amdgcn_mfma_f32_16x16x32_bf16(
                        af[tix], vf, vacc[tix], 0, 0, 0);
            }
        }

        asm volatile("s_waitcnt lgkmcnt(0)" ::: "memory");
        __builtin_amdgcn_s_barrier();
        asm volatile("" ::: "memory");

        // Pt := (I + Delta)^T
#pragma unroll
        for (int tix = 0; tix < 4; ++tix)
#pragma unroll
            for (int tjx = 0; tjx < 2; ++tjx) {
                int i0 = 64 * wr + 16 * tix + 4 * lg;
                int j = 32 * wc + 16 * tjx + lr;
                float v0 = acc[tix][tjx][0] + ((rd[tix][tjx] == 0) ? 1.f : 0.f);
                float v1 = acc[tix][tjx][1] + ((rd[tix][tjx] == 1) ? 1.f : 0.f);
                float v2 = acc[tix][tjx][2] + ((rd[tix][tjx] == 2) ? 1.f : 0.f);
                float v3 = acc[tix][tjx][3] + ((rd[tix][tjx] == 3) ? 1.f : 0.f);
                uint2 pk;
                pk.x = cvt_pk_bf16(v0, v1);
                pk.y = cvt_pk_bf16(v2, v3);
                int unit = (i0 >> 3) ^ (j & 7);
                *(uint2*)&Pt[(j << 7) | (unit << 3) | (i0 & 7)] = pk;
            }
        if (wc == 0 && lr == 0) {
#pragma unroll
            for (int tix = 0; tix < 4; ++tix) {
                int i0 = 64 * wr + 16 * tix + 4 * lg;
                const float* bp = &BsL[k][i0];
#pragma unroll
                for (int r = 0; r < 4; ++r) vacc[tix][r] += bp[r];
                uint2 pk;
                pk.x = cvt_pk_bf16(vacc[tix][0], vacc[tix][1]);
                pk.y = cvt_pk_bf16(vacc[tix][2], vacc[tix][3]);
                *(uint2*)&Pt[(128 << 7) | i0] = pk;
            }
        }
        int tmp = b0; b0 = b1; b1 = b2; b2 = tmp;
    }

    // write Delta (fp32) + v to global
    const size_t ci = (size_t)b * NCs + cs;
    float* D = Dm + ci * OO;
#pragma unroll
    for (int tix = 0; tix < 4; ++tix)
#pragma unroll
        for (int tjx = 0; tjx < 2; ++tjx) {
            int i0 = 64 * wr + 16 * tix + 4 * lg;
            int j = 32 * wc + 16 * tjx + lr;
#pragma unroll
            for (int r = 0; r < 4; ++r)
                D[(size_t)(i0 + r) * Hz + j] = acc[tix][tjx][r];
        }
    if (wc == 0 && lr == 0) {
        float* V = Vv + ci * Hz;
#pragma unroll
        for (int tix = 0; tix < 4; ++tix) {
            int i0 = 64 * wr + 16 * tix + 4 * lg;
#pragma unroll
            for (int r = 0; r < 4; ++r) V[i0 + r] = vacc[tix][r];
        }
    }
}

// -------- stage b: sequential over chunks, y_end = y + Delta y + v --------
__global__ __launch_bounds__(1024) void k_chunk_b(
    const float* __restrict__ Dm, const float* __restrict__ Vv,
    float* __restrict__ out, int t0, int Lsteps, int NCs) {
    const int b = blockIdx.x, tid = threadIdx.x;
    const int i = tid >> 3, q = tid & 7;
    __shared__ __align__(16) float yv[2][Hz];
    __shared__ float VvL[32 * Hz];

    if (tid < Hz) yv[0][tid] = out[((size_t)b * Sz + t0) * Hz + tid];
    for (int idx = tid; idx < NCs * Hz; idx += 1024)
        VvL[idx] = Vv[(size_t)b * NCs * Hz + idx];
    __syncthreads();

    const float4* D0 = (const float4*)(Dm + (size_t)b * NCs * OO);
    const int off = i * 32 + q * 4;        // float4 index: row i, col q*16
    float4 cur[4], n1[4], n2[4];
#pragma unroll
    for (int v = 0; v < 4; ++v) cur[v] = D0[off + v];
    {
        int c1i = (NCs > 1) ? 1 : 0;
        const float4* Dn = D0 + (size_t)c1i * (OO / 4);
#pragma unroll
        for (int v = 0; v < 4; ++v) n1[v] = Dn[off + v];
    }

    for (int cs = 0; cs < NCs; ++cs) {
        int nc2 = (cs + 2 < NCs) ? cs + 2 : NCs - 1;
        const float4* Dn = D0 + (size_t)nc2 * (OO / 4);
#pragma unroll
        for (int v = 0; v < 4; ++v) n2[v] = Dn[off + v];   // stays in flight

        const int cb = cs & 1;
        const float* yp = &yv[cb][q * 16];
        float s = 0.f;
#pragma unroll
        for (int v = 0; v < 4; ++v)
            s += cur[v].x * yp[v * 4 + 0] + cur[v].y * yp[v * 4 + 1] +
                 cur[v].z * yp[v * 4 + 2] + cur[v].w * yp[v * 4 + 3];
        s += __shfl_xor(s, 1);
        s += __shfl_xor(s, 2);
        s += __shfl_xor(s, 4);

        if (q == 0) {
            float yn = yv[cb][i] + s + VvL[cs * Hz + i];
            yv[cb ^ 1][i] = yn;
            int t_end = t0 + (cs + 1) * CHUNK;
            if (t_end < Sz)
                out[((size_t)b * Sz + t_end) * Hz + i] = yn;  // boundary row
        }
        asm volatile("s_waitcnt lgkmcnt(0)" ::: "memory");
        __builtin_amdgcn_s_barrier();
        asm volatile("" ::: "memory");
#pragma unroll
        for (int v = 0; v < 4; ++v) { cur[v] = n1[v]; n1[v] = n2[v]; }
    }
}

// -------- stage c: CHUNK-step replay per chunk (interior rows) --------
__global__ __launch_bounds__(1024) void k_chunk_c(
    const unsigned short* __restrict__ As, const float* __restrict__ Bs,
    float* __restrict__ out, int t0, int Lsteps, int NCs) {
    const int cs = blockIdx.x, b = blockIdx.y;
    const int tid = threadIdx.x;
    const int i = tid >> 3, p = tid & 7;
    const int t0c = t0 + cs * CHUNK;
    int Lc = Lsteps - cs * CHUNK; if (Lc > CHUNK) Lc = CHUNK;
    __shared__ __align__(16) float y[2][Hz];

    if (tid < Hz) y[0][tid] = out[((size_t)b * Sz + t0c) * Hz + tid];
    __syncthreads();

    const unsigned short* Abp = As + (size_t)(b * NCs + cs) * CHUNK * OO +
                                i * Hz + p * 16;
    const float* Bsb = Bs + (size_t)b * NT * Hz;
    float* outb = out + (size_t)b * Sz * Hz;

    u16x8 c0 = *(const u16x8*)(Abp);
    u16x8 c1 = *(const u16x8*)(Abp + 8);
    int l1 = (Lc > 1) ? 1 : 0;
    u16x8 d0 = *(const u16x8*)(Abp + (size_t)l1 * OO);
    u16x8 d1 = *(const u16x8*)(Abp + (size_t)l1 * OO + 8);

    for (int lt = 0; lt < Lc; ++lt) {
        int ln = lt + 2; if (ln > Lc - 1) ln = Lc - 1;
        u16x8 e0 = *(const u16x8*)(Abp + (size_t)ln * OO);
        u16x8 e1 = *(const u16x8*)(Abp + (size_t)ln * OO + 8);

        const int cur = lt & 1;
        const float4* yp = (const float4*)&y[cur][p * 16];
        float4 y0v = yp[0], y1v = yp[1], y2v = yp[2], y3v = yp[3];

        float s;
        s  = bf2f(c0[0]) * y0v.x + bf2f(c0[1]) * y0v.y +
             bf2f(c0[2]) * y0v.z + bf2f(c0[3]) * y0v.w;
        s += bf2f(c0[4]) * y1v.x + bf2f(c0[5]) * y1v.y +
             bf2f(c0[6]) * y1v.z + bf2f(c0[7]) * y1v.w;
        s += bf2f(c1[0]) * y2v.x + bf2f(c1[1]) * y2v.y +
             bf2f(c1[2]) * y2v.z + bf2f(c1[3]) * y2v.w;
        s += bf2f(c1[4]) * y3v.x + bf2f(c1[5]) * y3v.y +
             bf2f(c1[6]) * y3v.z + bf2f(c1[7]) * y3v.w;
        s += __shfl_xor(s, 1);
        s += __shfl_xor(s, 2);
        s += __shfl_xor(s, 4);

        if (p == 0) {
            int t = t0c + lt;
            float st = s + Bsb[(size_t)t * Hz + i];
            float yn = y[cur][i] + st;
            y[cur ^ 1][i] = yn;
            if (((t + 1) & (CHUNK - 1)) != 0)        // boundaries: stage b
                outb[(size_t)(t + 1) * Hz + i] = yn;
        }
        c0 = d0; c1 = d1; d0 = e0; d1 = e1;
        asm volatile("s_waitcnt lgkmcnt(0)" ::: "memory");
        __builtin_amdgcn_s_barrier();
        asm volatile("" ::: "memory");
    }
}

// -------- fallback (ws tiny) --------
__global__ __launch_bounds__(1024) void k_fused(const float* __restrict__ X,
                                                const float* __restrict__ initW,
                                                const float* __restrict__ initb,
                                                const float* __restrict__ WA,
                                                const float* __restrict__ WB,
                                                float* __restrict__ out) {
    const int b = blockIdx.x, tid = threadIdx.x;
    const int i = tid >> 3, p = tid & 7;
    __shared__ float y[2][Hz];
    __shared__ float u[KK];

    if (tid < Hz) {
        float a = initb[tid];
        const float* xr = X + (size_t)b * Sz * Dz;
        const float* wr = initW + (size_t)tid * Dz;
        for (int d = 0; d < Dz; ++d) a += xr[d] * wr[d];
        y[0][tid] = a;
        out[(size_t)b * Sz * Hz + tid] = a;
    }
    __syncthreads();

    for (int t = 0; t < NT; ++t) {
        if (tid < KK)
            u[tid] = (tid == 0) ? DT
                                : X[((size_t)b * Sz + t + 1) * Dz + tid - 1] * DT;
        __syncthreads();
        const int cur = t & 1;
        float partial = 0.f;
        for (int jj = 0; jj < 16; ++jj) {
            int j = p * 16 + jj;
            const float* wr = WA + (size_t)(i * Hz + j) * KK;
            float a = 0.f;
            for (int d = 0; d < KK; ++d) a += wr[d] * u[d];
            partial += a * y[cur][j];
        }
        partial += __shfl_xor(partial, 1);
        partial += __shfl_xor(partial, 2);
        partial += __shfl_xor(partial, 4);
        if (p == 0) {
            const float* wb = WB + (size_t)i * KK;
            float bv = 0.f;
            for (int d = 0; d < KK; ++d) bv += wb[d] * u[d];
            float yn = y[cur][i] + partial + bv;
            y[cur ^ 1][i] = yn;
            out[(size_t)b * Sz * Hz + (size_t)(t + 1) * Hz + i] = yn;
        }
        __syncthreads();
    }
}

extern "C" void kernel_launch(void* const* d_in, const int* in_sizes, int n_in,
                              void* d_out, int out_size, void* d_ws,
                              size_t ws_size, hipStream_t stream) {
    const float* X = (const float*)d_in[0];
    const float* initW = (const float*)d_in[1];
    const float* initb = (const float*)d_in[2];
    const float* WA = (const float*)d_in[3];
    const float* WB = (const float*)d_in[4];
    float* out = (float*)d_out;

    // ws layout
    const size_t WH_OFF = 0;                          // 2 MB
    const size_t WL_OFF = 2097152;                    // 2 MB
    const size_t WA0_OFF = 4194304;                   // 64 KB
    const size_t XH_OFF = 4259840;                    // 512 KB (4096 x 64)
    const size_t BS_OFF = 5308416;                    // 2 MB (8*511*128 f32)
    const size_t base = 7401472;
    const size_t PER_SC = (size_t)Bz * OO * 4 +       // Dm per chunk-col
                          (size_t)Bz * Hz * 4 +       // Vv per chunk-col
                          (size_t)Bz * CHUNK * OO * 2;// As per chunk-col
    const int NC = (NT + CHUNK - 1) / CHUNK;          // 64

    long SC_max = (ws_size > base) ? (long)((ws_size - base) / PER_SC) : 0;
    if (SC_max >= 2) {
        if (SC_max > 32) SC_max = 32;                 // VvL LDS cap in chunk_b
        int nS = (NC + (int)SC_max - 1) / (int)SC_max;
        int SC = (NC + nS - 1) / nS;
        SC = (SC + 1) & ~1;                           // even: Bz*Lpad % 128 == 0
        if (SC > 32) SC = 32;

        unsigned short* Wh = (unsigned short*)((char*)d_ws + WH_OFF);
        unsigned short* Wl = (unsigned short*)((char*)d_ws + WL_OFF);
        float* WA0d = (float*)((char*)d_ws + WA0_OFF);
        unsigned short* Xh = (unsigned short*)((char*)d_ws + XH_OFF);
        float* Bs = (float*)((char*)d_ws + BS_OFF);
        float* Dm = (float*)((char*)d_ws + base);
        float* Vv = (float*)((char*)d_ws + base + (size_t)SC * Bz * OO * 4);
        unsigned short* As = (unsigned short*)((char*)d_ws + base +
                                               (size_t)SC * Bz * OO * 4 +
                                               (size_t)SC * Bz * Hz * 4);

        k_wsplit<<<512, 256, 0, stream>>>(WA, Wh, Wl, WA0d);
        k_y0<<<4, 256, 0, stream>>>(X, initW, initb, out);
        k_bs<<<2044, 256, 0, stream>>>(X, WB, Bs);

        for (int c0 = 0; c0 < NC; c0 += SC) {
            int t0 = c0 * CHUNK;
            int Lsteps = NT - t0;
            if (Lsteps > SC * CHUNK) Lsteps = SC * CHUNK;
            int NCs = (Lsteps + CHUNK - 1) / CHUNK;
            int Lpad = ((NCs + 1) & ~1) * CHUNK;      // even chunks -> %16==0
            int prep_blocks = (Bz * Lpad * 8) / 256;
            int gemm_y = (Bz * Lpad) / 128;
            k_prep<<<prep_blocks, 256, 0, stream>>>(X, Xh, t0, Lsteps, Lpad);
            k_gemm_mfma<<<dim3(128, gemm_y), 256, 0, stream>>>(Xh, Wh, Wl,
                                                               WA0d, As);
            k_chunk_a<<<dim3(NCs, Bz), 512, 0, stream>>>(As, Bs, Dm, Vv, t0,
                                                         Lsteps, NCs);
            k_chunk_b<<<Bz, 1024, 0, stream>>>(Dm, Vv, out, t0, Lsteps, NCs);
            k_chunk_c<<<dim3(NCs, Bz), 1024, 0, stream>>>(As, Bs, out, t0,
                                                          Lsteps, NCs);
        }
    } else {
        k_fused<<<Bz, 1024, 0, stream>>>(X, initW, initb, WA, WB, out);
    }
}

// Round 14
// 177.747 us; speedup vs baseline: 1.2525x; 1.2525x over previous
//
#include <hip/hip_runtime.h>
#include <hip/hip_bf16.h>

// LinearCDE: y_{t+1} = y_t + A_t y_t + b_t, A_t = reshape(vf_A_W @ u_t, HxH),
// u_t = [1, X[:,t+1]] * DT.  CLIP=1e11 => tanh is identity to ~1e-10 rel.
//
// Round-14: CHUNK back to 16 (r13's CHUNK=8 added per-chunk overhead).
// chunk_a: column-split (each block owns 64 P-columns) with L2-PAIRED block
// ids: the two halves of a chunk sit at linear ids n and n+8 -> same XCD
// (id%8 heuristic) -> the duplicate A-stream hits that XCD's L2 (r12 failed
// because z-split put pairs 128 ids apart). 8 waves, 32x32 tiles, LDS 121KB.
#define DT 0.025f
#define Bz 8
#define Sz 512
#define Dz 64
#define Hz 128
#define NT 511            // S-1 steps
#define OO (Hz * Hz)      // 16384
#define KK (Dz + 1)       // 65
#define CHUNK 16

using short8 = __attribute__((ext_vector_type(8))) short;
using f32x4  = __attribute__((ext_vector_type(4))) float;
using u16x8  = __attribute__((ext_vector_type(8))) unsigned short;
using u16x4  = __attribute__((ext_vector_type(4))) unsigned short;

__device__ __forceinline__ float bf2f(unsigned short u) {
    union { unsigned int i; float f; } v;
    v.i = ((unsigned int)u) << 16;
    return v.f;
}
__device__ __forceinline__ unsigned short f2bf(float f) {
    union { float f; unsigned int i; } v;
    v.f = f;
    unsigned int u = v.i;
    return (unsigned short)((u + 0x7FFFu + ((u >> 16) & 1u)) >> 16);  // RNE
}
// packed f32x2 -> bf16x2 (RNE), gfx950 hw cvt
__device__ __forceinline__ unsigned int cvt_pk_bf16(float lo, float hi) {
    unsigned int r;
    asm("v_cvt_pk_bf16_f32 %0, %1, %2" : "=v"(r) : "v"(lo), "v"(hi));
    return r;
}

// async 16B global -> LDS (dest: wave-uniform base + lane*16)
__device__ __forceinline__ void dma16(const void* g, void* s) {
    __builtin_amdgcn_global_load_lds(
        (const __attribute__((address_space(1))) unsigned int*)g,
        (__attribute__((address_space(3))) unsigned int*)s, 16, 0, 0);
}

// -------- split vf_A_W: Wh/Wl bf16 [o][64] (d=1..64), WA0d = DT*col0 --------
__global__ __launch_bounds__(256) void k_wsplit(const float* __restrict__ WA,
                                                unsigned short* __restrict__ Wh,
                                                unsigned short* __restrict__ Wl,
                                                float* __restrict__ WA0d) {
    int idx = blockIdx.x * 256 + threadIdx.x;   // 512 blocks: 16384 o x 8 units
    int o = idx >> 3, u = idx & 7;
    const float* wr = WA + (size_t)o * KK + 1 + u * 8;
    u16x8 h = {}, lo = {};
#pragma unroll
    for (int j = 0; j < 8; ++j) {
        float v = wr[j];
        unsigned short hh = f2bf(v);
        h[j] = hh;
        lo[j] = f2bf(v - bf2f(hh));
    }
    *(u16x8*)(Wh + (size_t)o * 64 + u * 8) = h;
    *(u16x8*)(Wl + (size_t)o * 64 + u * 8) = lo;
    if (u == 0) WA0d[o] = DT * WA[(size_t)o * KK];
}

// -------- per-slice u: Xh bf16 [m'][64], m' = b*Lpad+lt, zero-padded --------
__global__ __launch_bounds__(256) void k_prep(const float* __restrict__ X,
                                              unsigned short* __restrict__ Xh,
                                              int t0, int Lsteps, int Lpad) {
    int idx = blockIdx.x * 256 + threadIdx.x;
    int m = idx >> 3, u = idx & 7;
    int b = m / Lpad, lt = m - b * Lpad;
    u16x8 h = {};
    if (lt < Lsteps) {
        const float* xr = X + ((size_t)b * Sz + t0 + lt + 1) * Dz + u * 8;
#pragma unroll
        for (int j = 0; j < 8; ++j) h[j] = f2bf(xr[j] * DT);
    }
    *(u16x8*)(Xh + (size_t)m * 64 + u * 8) = h;
}

// -------- y0 = X[:,0] @ init_W^T + init_b --------
__global__ __launch_bounds__(256) void k_y0(const float* __restrict__ X,
                                            const float* __restrict__ W,
                                            const float* __restrict__ bias,
                                            float* __restrict__ out) {
    int idx = blockIdx.x * 256 + threadIdx.x;
    int b = idx >> 7, h = idx & 127;
    const float* xr = X + (size_t)b * Sz * Dz;
    const float* wr = W + (size_t)h * Dz;
    float acc = bias[h];
    for (int d = 0; d < Dz; ++d) acc += xr[d] * wr[d];
    out[(size_t)b * Sz * Hz + h] = acc;
}

// -------- Bs[bt,h] --------
__global__ __launch_bounds__(256) void k_bs(const float* __restrict__ X,
                                            const float* __restrict__ WB,
                                            float* __restrict__ Bs) {
    int idx = blockIdx.x * 256 + threadIdx.x;
    int bt = idx >> 7, h = idx & 127;
    int b = bt / NT, t = bt - b * NT;
    const float* xr = X + ((size_t)b * Sz + t + 1) * Dz;
    const float* wr = WB + (size_t)h * KK;
    float acc = wr[0];
    for (int k = 0; k < Dz; ++k) acc += xr[k] * wr[1 + k];
    Bs[(size_t)bt * Hz + h] = acc * DT;
}

// -------- As GEMM via MFMA, 2-term split, step-major output --------
// block 256 thr (4 waves 2x2), tile 128 m' x 128 o, K=64.
// As[m'][o] = bf16( xh*(Wh+Wl) + DT*WA[o][0] )
__global__ __launch_bounds__(256, 3) void k_gemm_mfma(
    const unsigned short* __restrict__ Xh,
    const unsigned short* __restrict__ Wh, const unsigned short* __restrict__ Wl,
    const float* __restrict__ WA0d, unsigned short* __restrict__ As) {
    const int tid = threadIdx.x;
    const int w = tid >> 6, l = tid & 63;
    const int lr = l & 15, lg = l >> 4;
    const int wbt = w >> 1, wo = w & 1;
    const int o0 = blockIdx.x * 128;
    const int bt0 = blockIdx.y * 128;

    __shared__ __align__(16) unsigned short L[3 * 8192];  // Xh|Wh|Wl 128x64

#pragma unroll
    for (int q = 0; q < 4; ++q) {
        int seg = w * 4 + q;                 // 0..15 per buffer
        int du = seg * 64 + l;               // 0..1023 16B-units
        int row = du >> 3;
        int su = (du & ~7) | ((du & 7) ^ (row & 7));
        dma16(Xh + (size_t)bt0 * 64 + su * 8, &L[0 * 8192 + seg * 512]);
        dma16(Wh + (size_t)o0 * 64 + su * 8, &L[1 * 8192 + seg * 512]);
        dma16(Wl + (size_t)o0 * 64 + su * 8, &L[2 * 8192 + seg * 512]);
    }
    __syncthreads();   // implicit vmcnt(0): staging done

    f32x4 acc[4][4] = {};   // [oti][bti]
    const unsigned short* Xh_l = &L[0];
    const unsigned short* Wh_l = &L[8192];
    const unsigned short* Wl_l = &L[16384];

#pragma unroll
    for (int kk = 0; kk < 2; ++kk) {
        short8 xh[4], wh[4], wl[4];
#pragma unroll
        for (int t = 0; t < 4; ++t) {
            int btr = wbt * 64 + t * 16 + lr;
            int orr = wo * 64 + t * 16 + lr;
            int ux = (kk * 4 + lg) ^ (btr & 7);
            int uw = (kk * 4 + lg) ^ (orr & 7);
            xh[t] = *(const short8*)&Xh_l[btr * 64 + ux * 8];
            wh[t] = *(const short8*)&Wh_l[orr * 64 + uw * 8];
            wl[t] = *(const short8*)&Wl_l[orr * 64 + uw * 8];
        }
#pragma unroll
        for (int ot = 0; ot < 4; ++ot)
#pragma unroll
            for (int bt = 0; bt < 4; ++bt) {
                acc[ot][bt] = __builtin_amdgcn_mfma_f32_16x16x32_bf16(
                    wh[ot], xh[bt], acc[ot][bt], 0, 0, 0);
                acc[ot][bt] = __builtin_amdgcn_mfma_f32_16x16x32_bf16(
                    wl[ot], xh[bt], acc[ot][bt], 0, 0, 0);
            }
    }

    __syncthreads();                 // frag reads done; reuse L[0:16K u16] as T
    // T: 128 rows (m'_local) x 128 cols (o_local), 8B-unit XOR swizzle
    unsigned short* T = &L[0];
#pragma unroll
    for (int ot = 0; ot < 4; ++ot) {
        int obase = wo * 64 + ot * 16 + lg * 4;
        float4 wa = *(const float4*)&WA0d[o0 + obase];
#pragma unroll
        for (int bt = 0; bt < 4; ++bt) {
            int btl = wbt * 64 + bt * 16 + lr;
            u16x4 pk;
            pk[0] = f2bf(acc[ot][bt][0] + wa.x);
            pk[1] = f2bf(acc[ot][bt][1] + wa.y);
            pk[2] = f2bf(acc[ot][bt][2] + wa.z);
            pk[3] = f2bf(acc[ot][bt][3] + wa.w);
            int up = (obase >> 2) ^ ((btl & 15) << 1);
            *(u16x4*)&T[btl * 128 + up * 4] = pk;
        }
    }
    __syncthreads();
    // out-copy: per instruction, 16 lanes fully cover each 256B segment;
    // As row index = m' (global) directly.
    const int lane16 = tid & 15;
    const int segb = tid >> 4;           // 0..15
#pragma unroll
    for (int it = 0; it < 8; ++it) {
        int seg = it * 16 + segb;        // m'_local 0..127
        int up = (lane16 * 2) ^ ((seg & 15) << 1);
        u16x8 val = *(const u16x8*)&T[seg * 128 + up * 4];
        *(u16x8*)(As + (size_t)(bt0 + seg) * OO + o0 + lane16 * 8) = val;
    }
}

// -------- stage helper for chunk_a: 32KB contiguous, pre-swizzled source ----
// 512 threads: each lane issues 4 dma16 (seg = w*4+q, 32 segs x 1KB).
__device__ __forceinline__ void stage_a(const unsigned short* Astep,
                                        unsigned short* dstBuf, int w, int l) {
#pragma unroll
    for (int q = 0; q < 4; ++q) {
        int seg = w * 4 + q;                 // 0..31
        int du = seg * 64 + l;               // 0..2047 16B-units
        int row = du >> 4, cu = du & 15;
        int su = (du & ~15) | (cu ^ (row & 7));
        dma16(Astep + (size_t)su * 8, &dstBuf[seg * 512]);
    }
}

// -------- stage a: per-chunk Delta (128x128) and v via MFMA --------
// 1D grid 2*NCs*Bz; pair ids n and n+8 = the two 64-column halves of one
// (cs,b) chunk -> same XCD (id%8) -> duplicate A-stream hits L2.
// 512 thr = 8 waves (wr = w>>1 in [0,4): 32-row strip; wc = w&1: 32-col).
// A in LDS ring-3 (vmcnt(4)); Pt[65 rows] single-buffer, 2 barriers/step.
__global__ __launch_bounds__(512, 1) void k_chunk_a(
    const unsigned short* __restrict__ As, const float* __restrict__ Bs,
    float* __restrict__ Dm, float* __restrict__ Vv,
    int t0, int Lsteps, int NCs) {
    const int id = blockIdx.x;
    const int ch = (id >> 3) & 1;
    const int p = ((id >> 4) << 3) | (id & 7);     // 0..NCs*Bz-1
    const int cs = p % NCs, b = p / NCs;
    const int tid = threadIdx.x;
    const int w = tid >> 6, l = tid & 63;
    const int lr = l & 15, lg = l >> 4;
    const int wr = w >> 1, wc = w & 1;
    const int jb = ch * 64;
    int Lc = Lsteps - cs * CHUNK; if (Lc > CHUNK) Lc = CHUNK;

    __shared__ __align__(16) unsigned short AbufF[3 * OO];   // 96 KB ring
    __shared__ __align__(16) unsigned short Pt[65 * Hz];     // 16.6 KB (P^T;v)
    __shared__ __align__(16) float BsL[CHUNK][Hz];           // 8 KB

    const unsigned short* AsC = As + (size_t)(b * NCs + cs) * CHUNK * OO;

    stage_a(AsC, &AbufF[0], w, l);                    // buf 0 = step 0
    if (Lc > 1) stage_a(AsC + OO, &AbufF[OO], w, l);  // buf 1 = step 1

    // Pt = [I cols jb..jb+63 ; v=0] (swizzled rows; local row jl = j - jb)
    for (int idx = tid; idx < 65 * Hz; idx += 512) {
        int row = idx >> 7, col = idx & 127;
        unsigned short val = (row < 64 && col == jb + row)
                                 ? (unsigned short)0x3F80 : (unsigned short)0;
        int unit = (col >> 3) ^ (row & 7);
        Pt[(row << 7) | (unit << 3) | (col & 7)] = val;
    }
    const int t0c = t0 + cs * CHUNK;
    for (int idx = tid; idx < Lc * Hz; idx += 512) {
        int row = idx >> 7, col = idx & 127;
        BsL[row][col] = Bs[((size_t)b * NT + t0c + row) * Hz + col];
    }

    // identity: acc[tix][tjx][r] needs +1 iff r == rd[tix][tjx]
    int rd[2][2];
#pragma unroll
    for (int tix = 0; tix < 2; ++tix)
#pragma unroll
        for (int tjx = 0; tjx < 2; ++tjx)
            rd[tix][tjx] = (jb + 32 * wc + 16 * tjx + lr) -
                           (32 * wr + 16 * tix + 4 * lg);

    f32x4 acc[2][2] = {};
    f32x4 vacc[2] = {};
    int b0 = 0, b1 = 1, b2 = 2;
    const int kxor = lr & 7;

    for (int k = 0; k < Lc; ++k) {
        // buf[b0] (issued at k-2) complete; k+1's 4 loads stay in flight
        if (k + 1 < Lc) {
            asm volatile("s_waitcnt vmcnt(4) lgkmcnt(0)" ::: "memory");
        } else {
            asm volatile("s_waitcnt vmcnt(0) lgkmcnt(0)" ::: "memory");
        }
        __builtin_amdgcn_s_barrier();
        asm volatile("" ::: "memory");

        if (k + 2 < Lc)
            stage_a(AsC + (size_t)(k + 2) * OO, &AbufF[b2 * OO], w, l);

        const unsigned short* Ac = &AbufF[b0 * OO];
#pragma unroll
        for (int kt = 0; kt < 4; ++kt) {
            const int uoff = ((kt * 4 + lg) ^ kxor) << 3;
            short8 af0 = *(const short8*)&Ac[((32 * wr + lr) << 7) | uoff];
            short8 af1 = *(const short8*)&Ac[((32 * wr + 16 + lr) << 7) | uoff];
            short8 bf0 = *(const short8*)&Pt[((32 * wc + lr) << 7) | uoff];
            short8 bf1 = *(const short8*)&Pt[((32 * wc + 16 + lr) << 7) | uoff];
            acc[0][0] = __builtin_amdgcn_mfma_f32_16x16x32_bf16(af0, bf0,
                                                                acc[0][0], 0, 0, 0);
            acc[0][1] = __builtin_amdgcn_mfma_f32_16x16x32_bf16(af0, bf1,
                                                                acc[0][1], 0, 0, 0);
            acc[1][0] = __builtin_amdgcn_mfma_f32_16x16x32_bf16(af1, bf0,
                                                                acc[1][0], 0, 0, 0);
            acc[1][1] = __builtin_amdgcn_mfma_f32_16x16x32_bf16(af1, bf1,
                                                                acc[1][1], 0, 0, 0);
            if (ch == 0 && wc == 0) {
                short8 vf = *(const short8*)&Pt[(64 << 7) |
                                                ((kt * 4 + lg) << 3)];
                vacc[0] = __builtin_amdgcn_mfma_f32_16x16x32_bf16(af0, vf,
                                                                  vacc[0], 0, 0, 0);
                vacc[1] = __builtin_amdgcn_mfma_f32_16x16x32_bf16(af1, vf,
                                                                  vacc[1], 0, 0, 0);
            }
        }

        asm volatile("s_waitcnt lgkmcnt(0)" ::: "memory");
        __builtin_amdgcn_s_barrier();
        asm volatile("" ::: "memory");

        // Pt := (I + Delta)^T for this block's 64 columns
#pragma unroll
        for (int tix = 0; tix < 2; ++tix)
#pragma unroll
            for (int tjx = 0; tjx < 2; ++tjx) {
                int i0 = 32 * wr + 16 * tix + 4 * lg;
                int jl = 32 * wc + 16 * tjx + lr;
                float v0 = acc[tix][tjx][0] + ((rd[tix][tjx] == 0) ? 1.f : 0.f);
                float v1 = acc[tix][tjx][1] + ((rd[tix][tjx] == 1) ? 1.f : 0.f);
                float v2 = acc[tix][tjx][2] + ((rd[tix][tjx] == 2) ? 1.f : 0.f);
                float v3 = acc[tix][tjx][3] + ((rd[tix][tjx] == 3) ? 1.f : 0.f);
                uint2 pk;
                pk.x = cvt_pk_bf16(v0, v1);
                pk.y = cvt_pk_bf16(v2, v3);
                int unit = (i0 >> 3) ^ (jl & 7);
                *(uint2*)&Pt[(jl << 7) | (unit << 3) | (i0 & 7)] = pk;
            }
        if (ch == 0 && wc == 0 && lr == 0) {
#pragma unroll
            for (int tix = 0; tix < 2; ++tix) {
                int i0 = 32 * wr + 16 * tix + 4 * lg;
                const float* bp = &BsL[k][i0];
#pragma unroll
                for (int r = 0; r < 4; ++r) vacc[tix][r] += bp[r];
                uint2 pk;
                pk.x = cvt_pk_bf16(vacc[tix][0], vacc[tix][1]);
                pk.y = cvt_pk_bf16(vacc[tix][2], vacc[tix][3]);
                *(uint2*)&Pt[(64 << 7) | i0] = pk;
            }
        }
        int tmp = b0; b0 = b1; b1 = b2; b2 = tmp;
    }

    // write Delta (fp32) + v to global
    const size_t ci = (size_t)b * NCs + cs;
    float* D = Dm + ci * OO;
#pragma unroll
    for (int tix = 0; tix < 2; ++tix)
#pragma unroll
        for (int tjx = 0; tjx < 2; ++tjx) {
            int i0 = 32 * wr + 16 * tix + 4 * lg;
            int j = jb + 32 * wc + 16 * tjx + lr;
#pragma unroll
            for (int r = 0; r < 4; ++r)
                D[(size_t)(i0 + r) * Hz + j] = acc[tix][tjx][r];
        }
    if (ch == 0 && wc == 0 && lr == 0) {
        float* V = Vv + ci * Hz;
#pragma unroll
        for (int tix = 0; tix < 2; ++tix) {
            int i0 = 32 * wr + 16 * tix + 4 * lg;
#pragma unroll
            for (int r = 0; r < 4; ++r) V[i0 + r] = vacc[tix][r];
        }
    }
}

// -------- stage b: sequential over chunks, y_end = y + Delta y + v --------
__global__ __launch_bounds__(1024) void k_chunk_b(
    const float* __restrict__ Dm, const float* __restrict__ Vv,
    float* __restrict__ out, int t0, int Lsteps, int NCs) {
    const int b = blockIdx.x, tid = threadIdx.x;
    const int i = tid >> 3, q = tid & 7;
    __shared__ __align__(16) float yv[2][Hz];
    __shared__ float VvL[32 * Hz];

    if (tid < Hz) yv[0][tid] = out[((size_t)b * Sz + t0) * Hz + tid];
    for (int idx = tid; idx < NCs * Hz; idx += 1024)
        VvL[idx] = Vv[(size_t)b * NCs * Hz + idx];
    __syncthreads();

    const float4* D0 = (const float4*)(Dm + (size_t)b * NCs * OO);
    const int off = i * 32 + q * 4;        // float4 index: row i, col q*16
    float4 cur[4], n1[4], n2[4];
#pragma unroll
    for (int v = 0; v < 4; ++v) cur[v] = D0[off + v];
    {
        int c1i = (NCs > 1) ? 1 : 0;
        const float4* Dn = D0 + (size_t)c1i * (OO / 4);
#pragma unroll
        for (int v = 0; v < 4; ++v) n1[v] = Dn[off + v];
    }

    for (int cs = 0; cs < NCs; ++cs) {
        int nc2 = (cs + 2 < NCs) ? cs + 2 : NCs - 1;
        const float4* Dn = D0 + (size_t)nc2 * (OO / 4);
#pragma unroll
        for (int v = 0; v < 4; ++v) n2[v] = Dn[off + v];   // stays in flight

        const int cb = cs & 1;
        const float* yp = &yv[cb][q * 16];
        float s = 0.f;
#pragma unroll
        for (int v = 0; v < 4; ++v)
            s += cur[v].x * yp[v * 4 + 0] + cur[v].y * yp[v * 4 + 1] +
                 cur[v].z * yp[v * 4 + 2] + cur[v].w * yp[v * 4 + 3];
        s += __shfl_xor(s, 1);
        s += __shfl_xor(s, 2);
        s += __shfl_xor(s, 4);

        if (q == 0) {
            float yn = yv[cb][i] + s + VvL[cs * Hz + i];
            yv[cb ^ 1][i] = yn;
            int t_end = t0 + (cs + 1) * CHUNK;
            if (t_end < Sz)
                out[((size_t)b * Sz + t_end) * Hz + i] = yn;  // boundary row
        }
        asm volatile("s_waitcnt lgkmcnt(0)" ::: "memory");
        __builtin_amdgcn_s_barrier();
        asm volatile("" ::: "memory");
#pragma unroll
        for (int v = 0; v < 4; ++v) { cur[v] = n1[v]; n1[v] = n2[v]; }
    }
}

// -------- stage c: CHUNK-step replay per chunk (interior rows) --------
__global__ __launch_bounds__(1024) void k_chunk_c(
    const unsigned short* __restrict__ As, const float* __restrict__ Bs,
    float* __restrict__ out, int t0, int Lsteps, int NCs) {
    const int cs = blockIdx.x, b = blockIdx.y;
    const int tid = threadIdx.x;
    const int i = tid >> 3, p = tid & 7;
    const int t0c = t0 + cs * CHUNK;
    int Lc = Lsteps - cs * CHUNK; if (Lc > CHUNK) Lc = CHUNK;
    __shared__ __align__(16) float y[2][Hz];

    if (tid < Hz) y[0][tid] = out[((size_t)b * Sz + t0c) * Hz + tid];
    __syncthreads();

    const unsigned short* Abp = As + (size_t)(b * NCs + cs) * CHUNK * OO +
                                i * Hz + p * 16;
    const float* Bsb = Bs + (size_t)b * NT * Hz;
    float* outb = out + (size_t)b * Sz * Hz;

    u16x8 c0 = *(const u16x8*)(Abp);
    u16x8 c1 = *(const u16x8*)(Abp + 8);
    int l1 = (Lc > 1) ? 1 : 0;
    u16x8 d0 = *(const u16x8*)(Abp + (size_t)l1 * OO);
    u16x8 d1 = *(const u16x8*)(Abp + (size_t)l1 * OO + 8);

    for (int lt = 0; lt < Lc; ++lt) {
        int ln = lt + 2; if (ln > Lc - 1) ln = Lc - 1;
        u16x8 e0 = *(const u16x8*)(Abp + (size_t)ln * OO);
        u16x8 e1 = *(const u16x8*)(Abp + (size_t)ln * OO + 8);

        const int cur = lt & 1;
        const float4* yp = (const float4*)&y[cur][p * 16];
        float4 y0v = yp[0], y1v = yp[1], y2v = yp[2], y3v = yp[3];

        float s;
        s  = bf2f(c0[0]) * y0v.x + bf2f(c0[1]) * y0v.y +
             bf2f(c0[2]) * y0v.z + bf2f(c0[3]) * y0v.w;
        s += bf2f(c0[4]) * y1v.x + bf2f(c0[5]) * y1v.y +
             bf2f(c0[6]) * y1v.z + bf2f(c0[7]) * y1v.w;
        s += bf2f(c1[0]) * y2v.x + bf2f(c1[1]) * y2v.y +
             bf2f(c1[2]) * y2v.z + bf2f(c1[3]) * y2v.w;
        s += bf2f(c1[4]) * y3v.x + bf2f(c1[5]) * y3v.y +
             bf2f(c1[6]) * y3v.z + bf2f(c1[7]) * y3v.w;
        s += __shfl_xor(s, 1);
        s += __shfl_xor(s, 2);
        s += __shfl_xor(s, 4);

        if (p == 0) {
            int t = t0c + lt;
            float st = s + Bsb[(size_t)t * Hz + i];
            float yn = y[cur][i] + st;
            y[cur ^ 1][i] = yn;
            if (((t + 1) & (CHUNK - 1)) != 0)        // boundaries: stage b
                outb[(size_t)(t + 1) * Hz + i] = yn;
        }
        c0 = d0; c1 = d1; d0 = e0; d1 = e1;
        asm volatile("s_waitcnt lgkmcnt(0)" ::: "memory");
        __builtin_amdgcn_s_barrier();
        asm volatile("" ::: "memory");
    }
}

// -------- fallback (ws tiny) --------
__global__ __launch_bounds__(1024) void k_fused(const float* __restrict__ X,
                                                const float* __restrict__ initW,
                                                const float* __restrict__ initb,
                                                const float* __restrict__ WA,
                                                const float* __restrict__ WB,
                                                float* __restrict__ out) {
    const int b = blockIdx.x, tid = threadIdx.x;
    const int i = tid >> 3, p = tid & 7;
    __shared__ float y[2][Hz];
    __shared__ float u[KK];

    if (tid < Hz) {
        float a = initb[tid];
        const float* xr = X + (size_t)b * Sz * Dz;
        const float* wr = initW + (size_t)tid * Dz;
        for (int d = 0; d < Dz; ++d) a += xr[d] * wr[d];
        y[0][tid] = a;
        out[(size_t)b * Sz * Hz + tid] = a;
    }
    __syncthreads();

    for (int t = 0; t < NT; ++t) {
        if (tid < KK)
            u[tid] = (tid == 0) ? DT
                                : X[((size_t)b * Sz + t + 1) * Dz + tid - 1] * DT;
        __syncthreads();
        const int cur = t & 1;
        float partial = 0.f;
        for (int jj = 0; jj < 16; ++jj) {
            int j = p * 16 + jj;
            const float* wr = WA + (size_t)(i * Hz + j) * KK;
            float a = 0.f;
            for (int d = 0; d < KK; ++d) a += wr[d] * u[d];
            partial += a * y[cur][j];
        }
        partial += __shfl_xor(partial, 1);
        partial += __shfl_xor(partial, 2);
        partial += __shfl_xor(partial, 4);
        if (p == 0) {
            const float* wb = WB + (size_t)i * KK;
            float bv = 0.f;
            for (int d = 0; d < KK; ++d) bv += wb[d] * u[d];
            float yn = y[cur][i] + partial + bv;
            y[cur ^ 1][i] = yn;
            out[(size_t)b * Sz * Hz + (size_t)(t + 1) * Hz + i] = yn;
        }
        __syncthreads();
    }
}

extern "C" void kernel_launch(void* const* d_in, const int* in_sizes, int n_in,
                              void* d_out, int out_size, void* d_ws,
                              size_t ws_size, hipStream_t stream) {
    const float* X = (const float*)d_in[0];
    const float* initW = (const float*)d_in[1];
    const float* initb = (const float*)d_in[2];
    const float* WA = (const float*)d_in[3];
    const float* WB = (const float*)d_in[4];
    float* out = (float*)d_out;

    // ws layout
    const size_t WH_OFF = 0;                          // 2 MB
    const size_t WL_OFF = 2097152;                    // 2 MB
    const size_t WA0_OFF = 4194304;                   // 64 KB
    const size_t XH_OFF = 4259840;                    // 512 KB (4096 x 64)
    const size_t BS_OFF = 5308416;                    // 2 MB (8*511*128 f32)
    const size_t base = 7401472;
    const size_t PER_SC = (size_t)Bz * OO * 4 +       // Dm per chunk-col
                          (size_t)Bz * Hz * 4 +       // Vv per chunk-col
                          (size_t)Bz * CHUNK * OO * 2;// As per chunk-col
    const int NC = (NT + CHUNK - 1) / CHUNK;          // 32

    long SC_max = (ws_size > base) ? (long)((ws_size - base) / PER_SC) : 0;
    if (SC_max >= 1) {
        if (SC_max > NC) SC_max = NC;
        int nS = (NC + (int)SC_max - 1) / (int)SC_max;
        int SC = (NC + nS - 1) / nS;

        unsigned short* Wh = (unsigned short*)((char*)d_ws + WH_OFF);
        unsigned short* Wl = (unsigned short*)((char*)d_ws + WL_OFF);
        float* WA0d = (float*)((char*)d_ws + WA0_OFF);
        unsigned short* Xh = (unsigned short*)((char*)d_ws + XH_OFF);
        float* Bs = (float*)((char*)d_ws + BS_OFF);
        float* Dm = (float*)((char*)d_ws + base);
        float* Vv = (float*)((char*)d_ws + base + (size_t)SC * Bz * OO * 4);
        unsigned short* As = (unsigned short*)((char*)d_ws + base +
                                               (size_t)SC * Bz * OO * 4 +
                                               (size_t)SC * Bz * Hz * 4);

        k_wsplit<<<512, 256, 0, stream>>>(WA, Wh, Wl, WA0d);
        k_y0<<<4, 256, 0, stream>>>(X, initW, initb, out);
        k_bs<<<2044, 256, 0, stream>>>(X, WB, Bs);

        for (int c0 = 0; c0 < NC; c0 += SC) {
            int t0 = c0 * CHUNK;
            int Lsteps = NT - t0;
            if (Lsteps > SC * CHUNK) Lsteps = SC * CHUNK;
            int NCs = (Lsteps + CHUNK - 1) / CHUNK;
            int Lpad = NCs * CHUNK;
            k_prep<<<(Bz * Lpad * 8) / 256, 256, 0, stream>>>(X, Xh, t0,
                                                              Lsteps, Lpad);
            k_gemm_mfma<<<dim3(128, (Bz * Lpad) / 128), 256, 0, stream>>>(
                Xh, Wh, Wl, WA0d, As);
            k_chunk_a<<<2 * NCs * Bz, 512, 0, stream>>>(As, Bs, Dm, Vv, t0,
                                                        Lsteps, NCs);
            k_chunk_b<<<Bz, 1024, 0, stream>>>(Dm, Vv, out, t0, Lsteps, NCs);
            k_chunk_c<<<dim3(NCs, Bz), 1024, 0, stream>>>(As, Bs, out, t0,
                                                          Lsteps, NCs);
        }
    } else {
        k_fused<<<Bz, 1024, 0, stream>>>(X, initW, initb, WA, WB, out);
    }
}

// Round 15
// 163.917 us; speedup vs baseline: 1.3582x; 1.0844x over previous
//
#include <hip/hip_runtime.h>
#include <hip/hip_bf16.h>

// LinearCDE: y_{t+1} = y_t + A_t y_t + b_t, A_t = reshape(vf_A_W @ u_t, HxH),
// u_t = [1, X[:,t+1]] * DT.  CLIP=1e11 => tanh is identity to ~1e-10 rel.
//
// Round-15: exact round-8 pipeline (best measured, 170.1us) with ONE change:
// chunk_a uses Pt double-buffer + ring-2 A staging => ONE barrier per step
// (was 2). MFMAs read Pt[cur]/Abuf[k&1]; epilogue writes Pt[nxt]; stage k+1
// writes Abuf[(k+1)&1] whose readers were fenced at the previous barrier.
// LDS 64+66+8 = 138KB (same 1-block/CU footprint as r8).
#define DT 0.025f
#define Bz 8
#define Sz 512
#define Dz 64
#define Hz 128
#define NT 511            // S-1 steps
#define OO (Hz * Hz)      // 16384
#define KK (Dz + 1)       // 65
#define CHUNK 16

using short8 = __attribute__((ext_vector_type(8))) short;
using f32x4  = __attribute__((ext_vector_type(4))) float;
using u16x8  = __attribute__((ext_vector_type(8))) unsigned short;
using u16x4  = __attribute__((ext_vector_type(4))) unsigned short;

__device__ __forceinline__ float bf2f(unsigned short u) {
    union { unsigned int i; float f; } v;
    v.i = ((unsigned int)u) << 16;
    return v.f;
}
__device__ __forceinline__ unsigned short f2bf(float f) {
    union { float f; unsigned int i; } v;
    v.f = f;
    unsigned int u = v.i;
    return (unsigned short)((u + 0x7FFFu + ((u >> 16) & 1u)) >> 16);  // RNE
}
// packed f32x2 -> bf16x2 (RNE), gfx950 hw cvt
__device__ __forceinline__ unsigned int cvt_pk_bf16(float lo, float hi) {
    unsigned int r;
    asm("v_cvt_pk_bf16_f32 %0, %1, %2" : "=v"(r) : "v"(lo), "v"(hi));
    return r;
}

// async 16B global -> LDS (dest: wave-uniform base + lane*16)
__device__ __forceinline__ void dma16(const void* g, void* s) {
    __builtin_amdgcn_global_load_lds(
        (const __attribute__((address_space(1))) unsigned int*)g,
        (__attribute__((address_space(3))) unsigned int*)s, 16, 0, 0);
}

// -------- split vf_A_W: Wh/Wl bf16 [o][64] (d=1..64), WA0d = DT*col0 --------
__global__ __launch_bounds__(256) void k_wsplit(const float* __restrict__ WA,
                                                unsigned short* __restrict__ Wh,
                                                unsigned short* __restrict__ Wl,
                                                float* __restrict__ WA0d) {
    int idx = blockIdx.x * 256 + threadIdx.x;   // 512 blocks: 16384 o x 8 units
    int o = idx >> 3, u = idx & 7;
    const float* wr = WA + (size_t)o * KK + 1 + u * 8;
    u16x8 h = {}, lo = {};
#pragma unroll
    for (int j = 0; j < 8; ++j) {
        float v = wr[j];
        unsigned short hh = f2bf(v);
        h[j] = hh;
        lo[j] = f2bf(v - bf2f(hh));
    }
    *(u16x8*)(Wh + (size_t)o * 64 + u * 8) = h;
    *(u16x8*)(Wl + (size_t)o * 64 + u * 8) = lo;
    if (u == 0) WA0d[o] = DT * WA[(size_t)o * KK];
}

// -------- per-slice u: Xh bf16 [m'][64], m' = b*Lpad+lt, zero-padded --------
__global__ __launch_bounds__(256) void k_prep(const float* __restrict__ X,
                                              unsigned short* __restrict__ Xh,
                                              int t0, int Lsteps, int Lpad) {
    int idx = blockIdx.x * 256 + threadIdx.x;
    int m = idx >> 3, u = idx & 7;
    int b = m / Lpad, lt = m - b * Lpad;
    u16x8 h = {};
    if (lt < Lsteps) {
        const float* xr = X + ((size_t)b * Sz + t0 + lt + 1) * Dz + u * 8;
#pragma unroll
        for (int j = 0; j < 8; ++j) h[j] = f2bf(xr[j] * DT);
    }
    *(u16x8*)(Xh + (size_t)m * 64 + u * 8) = h;
}

// -------- y0 = X[:,0] @ init_W^T + init_b --------
__global__ __launch_bounds__(256) void k_y0(const float* __restrict__ X,
                                            const float* __restrict__ W,
                                            const float* __restrict__ bias,
                                            float* __restrict__ out) {
    int idx = blockIdx.x * 256 + threadIdx.x;
    int b = idx >> 7, h = idx & 127;
    const float* xr = X + (size_t)b * Sz * Dz;
    const float* wr = W + (size_t)h * Dz;
    float acc = bias[h];
    for (int d = 0; d < Dz; ++d) acc += xr[d] * wr[d];
    out[(size_t)b * Sz * Hz + h] = acc;
}

// -------- Bs[bt,h] --------
__global__ __launch_bounds__(256) void k_bs(const float* __restrict__ X,
                                            const float* __restrict__ WB,
                                            float* __restrict__ Bs) {
    int idx = blockIdx.x * 256 + threadIdx.x;
    int bt = idx >> 7, h = idx & 127;
    int b = bt / NT, t = bt - b * NT;
    const float* xr = X + ((size_t)b * Sz + t + 1) * Dz;
    const float* wr = WB + (size_t)h * KK;
    float acc = wr[0];
    for (int k = 0; k < Dz; ++k) acc += xr[k] * wr[1 + k];
    Bs[(size_t)bt * Hz + h] = acc * DT;
}

// -------- As GEMM via MFMA, 2-term split, step-major output --------
// block 256 thr (4 waves 2x2), tile 128 m' x 128 o, K=64.
// As[m'][o] = bf16( xh*(Wh+Wl) + DT*WA[o][0] ),  m' row = (b*NCs+cs)*16 + k
__global__ __launch_bounds__(256, 3) void k_gemm_mfma(
    const unsigned short* __restrict__ Xh,
    const unsigned short* __restrict__ Wh, const unsigned short* __restrict__ Wl,
    const float* __restrict__ WA0d, unsigned short* __restrict__ As) {
    const int tid = threadIdx.x;
    const int w = tid >> 6, l = tid & 63;
    const int lr = l & 15, lg = l >> 4;
    const int wbt = w >> 1, wo = w & 1;
    const int o0 = blockIdx.x * 128;
    const int bt0 = blockIdx.y * 128;

    __shared__ __align__(16) unsigned short L[3 * 8192];  // Xh|Wh|Wl 128x64

#pragma unroll
    for (int q = 0; q < 4; ++q) {
        int seg = w * 4 + q;                 // 0..15 per buffer
        int du = seg * 64 + l;               // 0..1023 16B-units
        int row = du >> 3;
        int su = (du & ~7) | ((du & 7) ^ (row & 7));
        dma16(Xh + (size_t)bt0 * 64 + su * 8, &L[0 * 8192 + seg * 512]);
        dma16(Wh + (size_t)o0 * 64 + su * 8, &L[1 * 8192 + seg * 512]);
        dma16(Wl + (size_t)o0 * 64 + su * 8, &L[2 * 8192 + seg * 512]);
    }
    __syncthreads();   // implicit vmcnt(0): staging done

    f32x4 acc[4][4] = {};   // [oti][bti]
    const unsigned short* Xh_l = &L[0];
    const unsigned short* Wh_l = &L[8192];
    const unsigned short* Wl_l = &L[16384];

#pragma unroll
    for (int kk = 0; kk < 2; ++kk) {
        short8 xh[4], wh[4], wl[4];
#pragma unroll
        for (int t = 0; t < 4; ++t) {
            int btr = wbt * 64 + t * 16 + lr;
            int orr = wo * 64 + t * 16 + lr;
            int ux = (kk * 4 + lg) ^ (btr & 7);
            int uw = (kk * 4 + lg) ^ (orr & 7);
            xh[t] = *(const short8*)&Xh_l[btr * 64 + ux * 8];
            wh[t] = *(const short8*)&Wh_l[orr * 64 + uw * 8];
            wl[t] = *(const short8*)&Wl_l[orr * 64 + uw * 8];
        }
#pragma unroll
        for (int ot = 0; ot < 4; ++ot)
#pragma unroll
            for (int bt = 0; bt < 4; ++bt) {
                acc[ot][bt] = __builtin_amdgcn_mfma_f32_16x16x32_bf16(
                    wh[ot], xh[bt], acc[ot][bt], 0, 0, 0);
                acc[ot][bt] = __builtin_amdgcn_mfma_f32_16x16x32_bf16(
                    wl[ot], xh[bt], acc[ot][bt], 0, 0, 0);
            }
    }

    __syncthreads();                 // frag reads done; reuse L[0:16K u16] as T
    // T: 128 rows (m'_local) x 128 cols (o_local), 8B-unit XOR swizzle
    unsigned short* T = &L[0];
#pragma unroll
    for (int ot = 0; ot < 4; ++ot) {
        int obase = wo * 64 + ot * 16 + lg * 4;
        float4 wa = *(const float4*)&WA0d[o0 + obase];
#pragma unroll
        for (int bt = 0; bt < 4; ++bt) {
            int btl = wbt * 64 + bt * 16 + lr;
            u16x4 pk;
            pk[0] = f2bf(acc[ot][bt][0] + wa.x);
            pk[1] = f2bf(acc[ot][bt][1] + wa.y);
            pk[2] = f2bf(acc[ot][bt][2] + wa.z);
            pk[3] = f2bf(acc[ot][bt][3] + wa.w);
            int up = (obase >> 2) ^ ((btl & 15) << 1);
            *(u16x4*)&T[btl * 128 + up * 4] = pk;
        }
    }
    __syncthreads();
    // out-copy: per instruction, 16 lanes fully cover each 256B segment
    const int lane16 = tid & 15;
    const int segb = tid >> 4;           // 0..15
#pragma unroll
    for (int it = 0; it < 8; ++it) {
        int seg = it * 16 + segb;        // m'_local 0..127
        int up = (lane16 * 2) ^ ((seg & 15) << 1);
        u16x8 val = *(const u16x8*)&T[seg * 128 + up * 4];
        *(u16x8*)(As + (size_t)(bt0 + seg) * OO + o0 + lane16 * 8) = val;
    }
}

// -------- stage helper for chunk_a: 32KB contiguous, pre-swizzled source ----
// 1024 threads: each lane issues 2 dma16 (seg = w*2+q, 32 segs x 1KB).
__device__ __forceinline__ void stage_a(const unsigned short* Astep,
                                        unsigned short* dstBuf, int w, int l) {
#pragma unroll
    for (int q = 0; q < 2; ++q) {
        int seg = w * 2 + q;                 // 0..31
        int du = seg * 64 + l;               // 0..2047 16B-units
        int row = du >> 4, cu = du & 15;
        int su = (du & ~15) | (cu ^ (row & 7));
        dma16(Astep + (size_t)su * 8, &dstBuf[seg * 512]);
    }
}

// per-step body (reads PTC + Abuf[KB&1], writes PTN; stage k+1; ONE barrier)
#define STEP_A(PTC, PTN, KS)                                                   \
    do {                                                                       \
        if ((KS) + 1 < Lc)                                                     \
            stage_a(AsC + (size_t)((KS) + 1) * OO,                             \
                    &AbufF[(((KS) + 1) & 1) * OO], w, l);                      \
        const unsigned short* Ac = &AbufF[((KS) & 1) * OO];                    \
        _Pragma("unroll")                                                      \
        for (int kt = 0; kt < 4; ++kt) {                                       \
            const int uoff = (((kt * 4 + lg) ^ kxor) << 3);                    \
            short8 af0 = *(const short8*)&Ac[((32 * wr + lr) << 7) | uoff];    \
            short8 af1 =                                                       \
                *(const short8*)&Ac[((32 * wr + 16 + lr) << 7) | uoff];        \
            short8 bf0 = *(const short8*)&PTC[((32 * wc + lr) << 7) | uoff];   \
            short8 bf1 =                                                       \
                *(const short8*)&PTC[((32 * wc + 16 + lr) << 7) | uoff];       \
            acc[0][0] = __builtin_amdgcn_mfma_f32_16x16x32_bf16(               \
                af0, bf0, acc[0][0], 0, 0, 0);                                 \
            acc[0][1] = __builtin_amdgcn_mfma_f32_16x16x32_bf16(               \
                af0, bf1, acc[0][1], 0, 0, 0);                                 \
            acc[1][0] = __builtin_amdgcn_mfma_f32_16x16x32_bf16(               \
                af1, bf0, acc[1][0], 0, 0, 0);                                 \
            acc[1][1] = __builtin_amdgcn_mfma_f32_16x16x32_bf16(               \
                af1, bf1, acc[1][1], 0, 0, 0);                                 \
            if (w < 8) {                                                       \
                short8 afv =                                                   \
                    *(const short8*)&Ac[((16 * w + lr) << 7) | uoff];          \
                short8 vf = *(const short8*)&PTC[(128 << 7) |                  \
                                                 ((kt * 4 + lg) << 3)];        \
                vacc = __builtin_amdgcn_mfma_f32_16x16x32_bf16(afv, vf, vacc,  \
                                                               0, 0, 0);       \
            }                                                                  \
        }                                                                      \
        _Pragma("unroll")                                                      \
        for (int tix = 0; tix < 2; ++tix)                                      \
            _Pragma("unroll")                                                  \
            for (int tjx = 0; tjx < 2; ++tjx) {                                \
                int i0 = 32 * wr + 16 * tix + 4 * lg;                          \
                int j = 32 * wc + 16 * tjx + lr;                               \
                float v0 =                                                     \
                    acc[tix][tjx][0] + ((rd[tix][tjx] == 0) ? 1.f : 0.f);      \
                float v1 =                                                     \
                    acc[tix][tjx][1] + ((rd[tix][tjx] == 1) ? 1.f : 0.f);      \
                float v2 =                                                     \
                    acc[tix][tjx][2] + ((rd[tix][tjx] == 2) ? 1.f : 0.f);      \
                float v3 =                                                     \
                    acc[tix][tjx][3] + ((rd[tix][tjx] == 3) ? 1.f : 0.f);      \
                uint2 pk;                                                      \
                pk.x = cvt_pk_bf16(v0, v1);                                    \
                pk.y = cvt_pk_bf16(v2, v3);                                    \
                int unit = (i0 >> 3) ^ (j & 7);                                \
                *(uint2*)&PTN[(j << 7) | (unit << 3) | (i0 & 7)] = pk;         \
            }                                                                  \
        if (w < 8 && lr == 0) {                                                \
            int i0 = 16 * w + 4 * lg;                                          \
            const float* bp = &BsL[(KS)][i0];                                  \
            uint2 pk;                                                          \
            vacc[0] += bp[0]; vacc[1] += bp[1];                                \
            vacc[2] += bp[2]; vacc[3] += bp[3];                                \
            pk.x = cvt_pk_bf16(vacc[0], vacc[1]);                              \
            pk.y = cvt_pk_bf16(vacc[2], vacc[3]);                              \
            *(uint2*)&PTN[(128 << 7) | i0] = pk;                               \
        }                                                                      \
        asm volatile("s_waitcnt vmcnt(0) lgkmcnt(0)" ::: "memory");            \
        __builtin_amdgcn_s_barrier();                                          \
        asm volatile("" ::: "memory");                                         \
    } while (0)

// -------- stage a: per-chunk Delta (128x128) and v via MFMA --------
// grid (NCs, Bz); 1024 thr = 16 waves (4x4); wave tile 32x32. A ring-2
// (stage k+1 during step k), Pt double-buffered => ONE barrier per step.
__global__ __launch_bounds__(1024) void k_chunk_a(
    const unsigned short* __restrict__ As, const float* __restrict__ Bs,
    float* __restrict__ Dm, float* __restrict__ Vv,
    int t0, int Lsteps, int NCs) {
    const int cs = blockIdx.x, b = blockIdx.y;
    const int tid = threadIdx.x;
    const int w = tid >> 6, l = tid & 63;
    const int lr = l & 15, lg = l >> 4;
    const int wr = w >> 2, wc = w & 3;
    int Lc = Lsteps - cs * CHUNK; if (Lc > CHUNK) Lc = CHUNK;

    __shared__ __align__(16) unsigned short AbufF[2 * OO];   // 64 KB ring-2
    __shared__ __align__(16) unsigned short PtA[129 * Hz];   // 33 KB
    __shared__ __align__(16) unsigned short PtB[129 * Hz];   // 33 KB
    __shared__ __align__(16) float BsL[CHUNK][Hz];           // 8 KB

    const unsigned short* AsC = As + (size_t)(b * NCs + cs) * CHUNK * OO;

    stage_a(AsC, &AbufF[0], w, l);                    // step 0 -> buf 0

    // PtA = [I ; v=0] (swizzled rows)
    for (int idx = tid; idx < 129 * Hz; idx += 1024) {
        int row = idx >> 7, col = idx & 127;
        unsigned short val = (row < Hz && row == col) ? (unsigned short)0x3F80
                                                      : (unsigned short)0;
        int unit = (col >> 3) ^ (row & 7);
        PtA[(row << 7) | (unit << 3) | (col & 7)] = val;
    }
    const int t0c = t0 + cs * CHUNK;
    for (int idx = tid; idx < Lc * Hz; idx += 1024) {
        int row = idx >> 7, col = idx & 127;
        BsL[row][col] = Bs[((size_t)b * NT + t0c + row) * Hz + col];
    }

    // identity: acc[tix][tjx][r] needs +1 iff r == rd[tix][tjx]
    int rd[2][2];
#pragma unroll
    for (int tix = 0; tix < 2; ++tix)
#pragma unroll
        for (int tjx = 0; tjx < 2; ++tjx)
            rd[tix][tjx] = (32 * wc + 16 * tjx + lr) -
                           (32 * wr + 16 * tix + 4 * lg);

    f32x4 acc[2][2] = {};
    f32x4 vacc = {};
    const int kxor = lr & 7;

    __syncthreads();                 // PtA + BsL + stage(0) done (vmcnt drain)

    for (int k2 = 0; k2 < CHUNK / 2; ++k2) {
        int k = 2 * k2;
        if (k >= Lc) break;
        STEP_A(PtA, PtB, k);
        if (k + 1 < Lc) STEP_A(PtB, PtA, k + 1);
    }

    // write Delta (fp32) + v to global
    const size_t ci = (size_t)b * NCs + cs;
    float* D = Dm + ci * OO;
#pragma unroll
    for (int tix = 0; tix < 2; ++tix)
#pragma unroll
        for (int tjx = 0; tjx < 2; ++tjx) {
            int i0 = 32 * wr + 16 * tix + 4 * lg;
            int j = 32 * wc + 16 * tjx + lr;
#pragma unroll
            for (int r = 0; r < 4; ++r)
                D[(size_t)(i0 + r) * Hz + j] = acc[tix][tjx][r];
        }
    if (w < 8 && lr == 0) {
        int i0 = 16 * w + 4 * lg;
        float* V = Vv + ci * Hz;
#pragma unroll
        for (int r = 0; r < 4; ++r) V[i0 + r] = vacc[r];
    }
}

// -------- stage b: sequential over chunks, y_end = y + Delta y + v --------
__global__ __launch_bounds__(1024) void k_chunk_b(
    const float* __restrict__ Dm, const float* __restrict__ Vv,
    float* __restrict__ out, int t0, int Lsteps, int NCs) {
    const int b = blockIdx.x, tid = threadIdx.x;
    const int i = tid >> 3, q = tid & 7;
    __shared__ __align__(16) float yv[2][Hz];
    __shared__ float VvL[32 * Hz];

    if (tid < Hz) yv[0][tid] = out[((size_t)b * Sz + t0) * Hz + tid];
    for (int idx = tid; idx < NCs * Hz; idx += 1024)
        VvL[idx] = Vv[(size_t)b * NCs * Hz + idx];
    __syncthreads();

    const float4* D0 = (const float4*)(Dm + (size_t)b * NCs * OO);
    const int off = i * 32 + q * 4;        // float4 index: row i, col q*16
    float4 cur[4], n1[4], n2[4];
#pragma unroll
    for (int v = 0; v < 4; ++v) cur[v] = D0[off + v];
    {
        int c1i = (NCs > 1) ? 1 : 0;
        const float4* Dn = D0 + (size_t)c1i * (OO / 4);
#pragma unroll
        for (int v = 0; v < 4; ++v) n1[v] = Dn[off + v];
    }

    for (int cs = 0; cs < NCs; ++cs) {
        int nc2 = (cs + 2 < NCs) ? cs + 2 : NCs - 1;
        const float4* Dn = D0 + (size_t)nc2 * (OO / 4);
#pragma unroll
        for (int v = 0; v < 4; ++v) n2[v] = Dn[off + v];   // stays in flight

        const int cb = cs & 1;
        const float* yp = &yv[cb][q * 16];
        float s = 0.f;
#pragma unroll
        for (int v = 0; v < 4; ++v)
            s += cur[v].x * yp[v * 4 + 0] + cur[v].y * yp[v * 4 + 1] +
                 cur[v].z * yp[v * 4 + 2] + cur[v].w * yp[v * 4 + 3];
        s += __shfl_xor(s, 1);
        s += __shfl_xor(s, 2);
        s += __shfl_xor(s, 4);

        if (q == 0) {
            float yn = yv[cb][i] + s + VvL[cs * Hz + i];
            yv[cb ^ 1][i] = yn;
            int t_end = t0 + (cs + 1) * CHUNK;
            if (t_end < Sz)
                out[((size_t)b * Sz + t_end) * Hz + i] = yn;  // boundary row
        }
        asm volatile("s_waitcnt lgkmcnt(0)" ::: "memory");
        __builtin_amdgcn_s_barrier();
        asm volatile("" ::: "memory");
#pragma unroll
        for (int v = 0; v < 4; ++v) { cur[v] = n1[v]; n1[v] = n2[v]; }
    }
}

// -------- stage c: CHUNK-step replay per chunk (interior rows) --------
__global__ __launch_bounds__(1024) void k_chunk_c(
    const unsigned short* __restrict__ As, const float* __restrict__ Bs,
    float* __restrict__ out, int t0, int Lsteps, int NCs) {
    const int cs = blockIdx.x, b = blockIdx.y;
    const int tid = threadIdx.x;
    const int i = tid >> 3, p = tid & 7;
    const int t0c = t0 + cs * CHUNK;
    int Lc = Lsteps - cs * CHUNK; if (Lc > CHUNK) Lc = CHUNK;
    __shared__ __align__(16) float y[2][Hz];

    if (tid < Hz) y[0][tid] = out[((size_t)b * Sz + t0c) * Hz + tid];
    __syncthreads();

    const unsigned short* Abp = As + (size_t)(b * NCs + cs) * CHUNK * OO +
                                i * Hz + p * 16;
    const float* Bsb = Bs + (size_t)b * NT * Hz;
    float* outb = out + (size_t)b * Sz * Hz;

    u16x8 c0 = *(const u16x8*)(Abp);
    u16x8 c1 = *(const u16x8*)(Abp + 8);
    int l1 = (Lc > 1) ? 1 : 0;
    u16x8 d0 = *(const u16x8*)(Abp + (size_t)l1 * OO);
    u16x8 d1 = *(const u16x8*)(Abp + (size_t)l1 * OO + 8);

    for (int lt = 0; lt < Lc; ++lt) {
        int ln = lt + 2; if (ln > Lc - 1) ln = Lc - 1;
        u16x8 e0 = *(const u16x8*)(Abp + (size_t)ln * OO);
        u16x8 e1 = *(const u16x8*)(Abp + (size_t)ln * OO + 8);

        const int cur = lt & 1;
        const float4* yp = (const float4*)&y[cur][p * 16];
        float4 y0v = yp[0], y1v = yp[1], y2v = yp[2], y3v = yp[3];

        float s;
        s  = bf2f(c0[0]) * y0v.x + bf2f(c0[1]) * y0v.y +
             bf2f(c0[2]) * y0v.z + bf2f(c0[3]) * y0v.w;
        s += bf2f(c0[4]) * y1v.x + bf2f(c0[5]) * y1v.y +
             bf2f(c0[6]) * y1v.z + bf2f(c0[7]) * y1v.w;
        s += bf2f(c1[0]) * y2v.x + bf2f(c1[1]) * y2v.y +
             bf2f(c1[2]) * y2v.z + bf2f(c1[3]) * y2v.w;
        s += bf2f(c1[4]) * y3v.x + bf2f(c1[5]) * y3v.y +
             bf2f(c1[6]) * y3v.z + bf2f(c1[7]) * y3v.w;
        s += __shfl_xor(s, 1);
        s += __shfl_xor(s, 2);
        s += __shfl_xor(s, 4);

        if (p == 0) {
            int t = t0c + lt;
            float st = s + Bsb[(size_t)t * Hz + i];
            float yn = y[cur][i] + st;
            y[cur ^ 1][i] = yn;
            if (((t + 1) & (CHUNK - 1)) != 0)        // boundaries: stage b
                outb[(size_t)(t + 1) * Hz + i] = yn;
        }
        c0 = d0; c1 = d1; d0 = e0; d1 = e1;
        asm volatile("s_waitcnt lgkmcnt(0)" ::: "memory");
        __builtin_amdgcn_s_barrier();
        asm volatile("" ::: "memory");
    }
}

// -------- fallback (ws tiny) --------
__global__ __launch_bounds__(1024) void k_fused(const float* __restrict__ X,
                                                const float* __restrict__ initW,
                                                const float* __restrict__ initb,
                                                const float* __restrict__ WA,
                                                const float* __restrict__ WB,
                                                float* __restrict__ out) {
    const int b = blockIdx.x, tid = threadIdx.x;
    const int i = tid >> 3, p = tid & 7;
    __shared__ float y[2][Hz];
    __shared__ float u[KK];

    if (tid < Hz) {
        float a = initb[tid];
        const float* xr = X + (size_t)b * Sz * Dz;
        const float* wr = initW + (size_t)tid * Dz;
        for (int d = 0; d < Dz; ++d) a += xr[d] * wr[d];
        y[0][tid] = a;
        out[(size_t)b * Sz * Hz + tid] = a;
    }
    __syncthreads();

    for (int t = 0; t < NT; ++t) {
        if (tid < KK)
            u[tid] = (tid == 0) ? DT
                                : X[((size_t)b * Sz + t + 1) * Dz + tid - 1] * DT;
        __syncthreads();
        const int cur = t & 1;
        float partial = 0.f;
        for (int jj = 0; jj < 16; ++jj) {
            int j = p * 16 + jj;
            const float* wr = WA + (size_t)(i * Hz + j) * KK;
            float a = 0.f;
            for (int d = 0; d < KK; ++d) a += wr[d] * u[d];
            partial += a * y[cur][j];
        }
        partial += __shfl_xor(partial, 1);
        partial += __shfl_xor(partial, 2);
        partial += __shfl_xor(partial, 4);
        if (p == 0) {
            const float* wb = WB + (size_t)i * KK;
            float bv = 0.f;
            for (int d = 0; d < KK; ++d) bv += wb[d] * u[d];
            float yn = y[cur][i] + partial + bv;
            y[cur ^ 1][i] = yn;
            out[(size_t)b * Sz * Hz + (size_t)(t + 1) * Hz + i] = yn;
        }
        __syncthreads();
    }
}

extern "C" void kernel_launch(void* const* d_in, const int* in_sizes, int n_in,
                              void* d_out, int out_size, void* d_ws,
                              size_t ws_size, hipStream_t stream) {
    const float* X = (const float*)d_in[0];
    const float* initW = (const float*)d_in[1];
    const float* initb = (const float*)d_in[2];
    const float* WA = (const float*)d_in[3];
    const float* WB = (const float*)d_in[4];
    float* out = (float*)d_out;

    // ws layout
    const size_t WH_OFF = 0;                          // 2 MB
    const size_t WL_OFF = 2097152;                    // 2 MB
    const size_t WA0_OFF = 4194304;                   // 64 KB
    const size_t XH_OFF = 4259840;                    // 512 KB (4096 x 64)
    const size_t BS_OFF = 5308416;                    // 2 MB (8*511*128 f32)
    const size_t base = 7401472;
    const size_t PER_SC = (size_t)Bz * OO * 4 +       // Dm per chunk-col
                          (size_t)Bz * Hz * 4 +       // Vv per chunk-col
                          (size_t)Bz * CHUNK * OO * 2;// As per chunk-col
    const int NC = (NT + CHUNK - 1) / CHUNK;          // 32

    long SC_max = (ws_size > base) ? (long)((ws_size - base) / PER_SC) : 0;
    if (SC_max >= 1) {
        if (SC_max > NC) SC_max = NC;
        int nS = (NC + (int)SC_max - 1) / (int)SC_max;
        int SC = (NC + nS - 1) / nS;

        unsigned short* Wh = (unsigned short*)((char*)d_ws + WH_OFF);
        unsigned short* Wl = (unsigned short*)((char*)d_ws + WL_OFF);
        float* WA0d = (float*)((char*)d_ws + WA0_OFF);
        unsigned short* Xh = (unsigned short*)((char*)d_ws + XH_OFF);
        float* Bs = (float*)((char*)d_ws + BS_OFF);
        float* Dm = (float*)((char*)d_ws + base);
        float* Vv = (float*)((char*)d_ws + base + (size_t)SC * Bz * OO * 4);
        unsigned short* As = (unsigned short*)((char*)d_ws + base +
                                               (size_t)SC * Bz * OO * 4 +
                                               (size_t)SC * Bz * Hz * 4);

        k_wsplit<<<512, 256, 0, stream>>>(WA, Wh, Wl, WA0d);
        k_y0<<<4, 256, 0, stream>>>(X, initW, initb, out);
        k_bs<<<2044, 256, 0, stream>>>(X, WB, Bs);

        for (int c0 = 0; c0 < NC; c0 += SC) {
            int t0 = c0 * CHUNK;
            int Lsteps = NT - t0;
            if (Lsteps > SC * CHUNK) Lsteps = SC * CHUNK;
            int NCs = (Lsteps + CHUNK - 1) / CHUNK;
            int Lpad = NCs * CHUNK;
            k_prep<<<(Bz * Lpad * 8) / 256, 256, 0, stream>>>(X, Xh, t0,
                                                              Lsteps, Lpad);
            k_gemm_mfma<<<dim3(128, (Bz * Lpad) / 128), 256, 0, stream>>>(
                Xh, Wh, Wl, WA0d, As);
            k_chunk_a<<<dim3(NCs, Bz), 1024, 0, stream>>>(As, Bs, Dm, Vv, t0,
                                                          Lsteps, NCs);
            k_chunk_b<<<Bz, 1024, 0, stream>>>(Dm, Vv, out, t0, Lsteps, NCs);
            k_chunk_c<<<dim3(NCs, Bz), 1024, 0, stream>>>(As, Bs, out, t0,
                                                          Lsteps, NCs);
        }
    } else {
        k_fused<<<Bz, 1024, 0, stream>>>(X, initW, initb, WA, WB, out);
    }
}

// Round 16
// 154.705 us; speedup vs baseline: 1.4390x; 1.0595x over previous
//
#include <hip/hip_runtime.h>
#include <hip/hip_bf16.h>

// LinearCDE: y_{t+1} = y_t + A_t y_t + b_t, A_t = reshape(vf_A_W @ u_t, HxH),
// u_t = [1, X[:,t+1]] * DT.  CLIP=1e11 => tanh is identity to ~1e-10 rel.
//
// Round-16: r15 (best, 163.9us) + prologue consolidation: wsplit/y0/bs/prep
// merged into ONE k_setup dispatch (independent work, branch on blockIdx
// range) -> 8 dispatches/call down to 5. Multi-slice fallback keeps per-slice
// prep. chunk_a/b/c and gemm byte-identical to r15.
#define DT 0.025f
#define Bz 8
#define Sz 512
#define Dz 64
#define Hz 128
#define NT 511            // S-1 steps
#define OO (Hz * Hz)      // 16384
#define KK (Dz + 1)       // 65
#define CHUNK 16

using short8 = __attribute__((ext_vector_type(8))) short;
using f32x4  = __attribute__((ext_vector_type(4))) float;
using u16x8  = __attribute__((ext_vector_type(8))) unsigned short;
using u16x4  = __attribute__((ext_vector_type(4))) unsigned short;

__device__ __forceinline__ float bf2f(unsigned short u) {
    union { unsigned int i; float f; } v;
    v.i = ((unsigned int)u) << 16;
    return v.f;
}
__device__ __forceinline__ unsigned short f2bf(float f) {
    union { float f; unsigned int i; } v;
    v.f = f;
    unsigned int u = v.i;
    return (unsigned short)((u + 0x7FFFu + ((u >> 16) & 1u)) >> 16);  // RNE
}
// packed f32x2 -> bf16x2 (RNE), gfx950 hw cvt
__device__ __forceinline__ unsigned int cvt_pk_bf16(float lo, float hi) {
    unsigned int r;
    asm("v_cvt_pk_bf16_f32 %0, %1, %2" : "=v"(r) : "v"(lo), "v"(hi));
    return r;
}

// async 16B global -> LDS (dest: wave-uniform base + lane*16)
__device__ __forceinline__ void dma16(const void* g, void* s) {
    __builtin_amdgcn_global_load_lds(
        (const __attribute__((address_space(1))) unsigned int*)g,
        (__attribute__((address_space(3))) unsigned int*)s, 16, 0, 0);
}

// ---------------- prologue work items (device functions) ----------------
__device__ __forceinline__ void do_wsplit(int bid, int tid,
                                          const float* __restrict__ WA,
                                          unsigned short* __restrict__ Wh,
                                          unsigned short* __restrict__ Wl,
                                          float* __restrict__ WA0d) {
    int idx = bid * 256 + tid;                  // 512 blocks: 16384 o x 8 units
    int o = idx >> 3, u = idx & 7;
    const float* wr = WA + (size_t)o * KK + 1 + u * 8;
    u16x8 h = {}, lo = {};
#pragma unroll
    for (int j = 0; j < 8; ++j) {
        float v = wr[j];
        unsigned short hh = f2bf(v);
        h[j] = hh;
        lo[j] = f2bf(v - bf2f(hh));
    }
    *(u16x8*)(Wh + (size_t)o * 64 + u * 8) = h;
    *(u16x8*)(Wl + (size_t)o * 64 + u * 8) = lo;
    if (u == 0) WA0d[o] = DT * WA[(size_t)o * KK];
}

__device__ __forceinline__ void do_y0(int bid, int tid,
                                      const float* __restrict__ X,
                                      const float* __restrict__ W,
                                      const float* __restrict__ bias,
                                      float* __restrict__ out) {
    int idx = bid * 256 + tid;                  // 4 blocks
    int b = idx >> 7, h = idx & 127;
    const float* xr = X + (size_t)b * Sz * Dz;
    const float* wr = W + (size_t)h * Dz;
    float acc = bias[h];
    for (int d = 0; d < Dz; ++d) acc += xr[d] * wr[d];
    out[(size_t)b * Sz * Hz + h] = acc;
}

__device__ __forceinline__ void do_bs(int bid, int tid,
                                      const float* __restrict__ X,
                                      const float* __restrict__ WB,
                                      float* __restrict__ Bs) {
    int idx = bid * 256 + tid;                  // 2044 blocks
    int bt = idx >> 7, h = idx & 127;
    int b = bt / NT, t = bt - b * NT;
    const float* xr = X + ((size_t)b * Sz + t + 1) * Dz;
    const float* wr = WB + (size_t)h * KK;
    float acc = wr[0];
    for (int k = 0; k < Dz; ++k) acc += xr[k] * wr[1 + k];
    Bs[(size_t)bt * Hz + h] = acc * DT;
}

__device__ __forceinline__ void do_prep(int bid, int tid,
                                        const float* __restrict__ X,
                                        unsigned short* __restrict__ Xh,
                                        int t0, int Lsteps, int Lpad) {
    int idx = bid * 256 + tid;
    int m = idx >> 3, u = idx & 7;
    int b = m / Lpad, lt = m - b * Lpad;
    u16x8 h = {};
    if (lt < Lsteps) {
        const float* xr = X + ((size_t)b * Sz + t0 + lt + 1) * Dz + u * 8;
#pragma unroll
        for (int j = 0; j < 8; ++j) h[j] = f2bf(xr[j] * DT);
    }
    *(u16x8*)(Xh + (size_t)m * 64 + u * 8) = h;
}

// -------- merged prologue (single-slice fast path) --------
// blocks [0,512): wsplit | [512,516): y0 | [516,2560): bs | [2560,2560+P): prep
__global__ __launch_bounds__(256) void k_setup(
    const float* __restrict__ X, const float* __restrict__ initW,
    const float* __restrict__ initb, const float* __restrict__ WA,
    const float* __restrict__ WB, unsigned short* __restrict__ Wh,
    unsigned short* __restrict__ Wl, float* __restrict__ WA0d,
    float* __restrict__ Bs, unsigned short* __restrict__ Xh,
    float* __restrict__ out, int Lsteps, int Lpad) {
    const int bid = blockIdx.x, tid = threadIdx.x;
    if (bid < 512) {
        do_wsplit(bid, tid, WA, Wh, Wl, WA0d);
    } else if (bid < 516) {
        do_y0(bid - 512, tid, X, initW, initb, out);
    } else if (bid < 2560) {
        do_bs(bid - 516, tid, X, WB, Bs);
    } else {
        do_prep(bid - 2560, tid, X, Xh, 0, Lsteps, Lpad);
    }
}

// standalone variants for the multi-slice fallback path
__global__ __launch_bounds__(256) void k_setup_nosplice(
    const float* __restrict__ X, const float* __restrict__ initW,
    const float* __restrict__ initb, const float* __restrict__ WA,
    const float* __restrict__ WB, unsigned short* __restrict__ Wh,
    unsigned short* __restrict__ Wl, float* __restrict__ WA0d,
    float* __restrict__ Bs, float* __restrict__ out) {
    const int bid = blockIdx.x, tid = threadIdx.x;
    if (bid < 512) {
        do_wsplit(bid, tid, WA, Wh, Wl, WA0d);
    } else if (bid < 516) {
        do_y0(bid - 512, tid, X, initW, initb, out);
    } else {
        do_bs(bid - 516, tid, X, WB, Bs);
    }
}
__global__ __launch_bounds__(256) void k_prep(const float* __restrict__ X,
                                              unsigned short* __restrict__ Xh,
                                              int t0, int Lsteps, int Lpad) {
    do_prep(blockIdx.x, threadIdx.x, X, Xh, t0, Lsteps, Lpad);
}

// -------- As GEMM via MFMA, 2-term split, step-major output --------
// block 256 thr (4 waves 2x2), tile 128 m' x 128 o, K=64.
// As[m'][o] = bf16( xh*(Wh+Wl) + DT*WA[o][0] ),  m' row = (b*NCs+cs)*16 + k
__global__ __launch_bounds__(256, 3) void k_gemm_mfma(
    const unsigned short* __restrict__ Xh,
    const unsigned short* __restrict__ Wh, const unsigned short* __restrict__ Wl,
    const float* __restrict__ WA0d, unsigned short* __restrict__ As) {
    const int tid = threadIdx.x;
    const int w = tid >> 6, l = tid & 63;
    const int lr = l & 15, lg = l >> 4;
    const int wbt = w >> 1, wo = w & 1;
    const int o0 = blockIdx.x * 128;
    const int bt0 = blockIdx.y * 128;

    __shared__ __align__(16) unsigned short L[3 * 8192];  // Xh|Wh|Wl 128x64

#pragma unroll
    for (int q = 0; q < 4; ++q) {
        int seg = w * 4 + q;                 // 0..15 per buffer
        int du = seg * 64 + l;               // 0..1023 16B-units
        int row = du >> 3;
        int su = (du & ~7) | ((du & 7) ^ (row & 7));
        dma16(Xh + (size_t)bt0 * 64 + su * 8, &L[0 * 8192 + seg * 512]);
        dma16(Wh + (size_t)o0 * 64 + su * 8, &L[1 * 8192 + seg * 512]);
        dma16(Wl + (size_t)o0 * 64 + su * 8, &L[2 * 8192 + seg * 512]);
    }
    __syncthreads();   // implicit vmcnt(0): staging done

    f32x4 acc[4][4] = {};   // [oti][bti]
    const unsigned short* Xh_l = &L[0];
    const unsigned short* Wh_l = &L[8192];
    const unsigned short* Wl_l = &L[16384];

#pragma unroll
    for (int kk = 0; kk < 2; ++kk) {
        short8 xh[4], wh[4], wl[4];
#pragma unroll
        for (int t = 0; t < 4; ++t) {
            int btr = wbt * 64 + t * 16 + lr;
            int orr = wo * 64 + t * 16 + lr;
            int ux = (kk * 4 + lg) ^ (btr & 7);
            int uw = (kk * 4 + lg) ^ (orr & 7);
            xh[t] = *(const short8*)&Xh_l[btr * 64 + ux * 8];
            wh[t] = *(const short8*)&Wh_l[orr * 64 + uw * 8];
            wl[t] = *(const short8*)&Wl_l[orr * 64 + uw * 8];
        }
#pragma unroll
        for (int ot = 0; ot < 4; ++ot)
#pragma unroll
            for (int bt = 0; bt < 4; ++bt) {
                acc[ot][bt] = __builtin_amdgcn_mfma_f32_16x16x32_bf16(
                    wh[ot], xh[bt], acc[ot][bt], 0, 0, 0);
                acc[ot][bt] = __builtin_amdgcn_mfma_f32_16x16x32_bf16(
                    wl[ot], xh[bt], acc[ot][bt], 0, 0, 0);
            }
    }

    __syncthreads();                 // frag reads done; reuse L[0:16K u16] as T
    // T: 128 rows (m'_local) x 128 cols (o_local), 8B-unit XOR swizzle
    unsigned short* T = &L[0];
#pragma unroll
    for (int ot = 0; ot < 4; ++ot) {
        int obase = wo * 64 + ot * 16 + lg * 4;
        float4 wa = *(const float4*)&WA0d[o0 + obase];
#pragma unroll
        for (int bt = 0; bt < 4; ++bt) {
            int btl = wbt * 64 + bt * 16 + lr;
            u16x4 pk;
            pk[0] = f2bf(acc[ot][bt][0] + wa.x);
            pk[1] = f2bf(acc[ot][bt][1] + wa.y);
            pk[2] = f2bf(acc[ot][bt][2] + wa.z);
            pk[3] = f2bf(acc[ot][bt][3] + wa.w);
            int up = (obase >> 2) ^ ((btl & 15) << 1);
            *(u16x4*)&T[btl * 128 + up * 4] = pk;
        }
    }
    __syncthreads();
    // out-copy: per instruction, 16 lanes fully cover each 256B segment
    const int lane16 = tid & 15;
    const int segb = tid >> 4;           // 0..15
#pragma unroll
    for (int it = 0; it < 8; ++it) {
        int seg = it * 16 + segb;        // m'_local 0..127
        int up = (lane16 * 2) ^ ((seg & 15) << 1);
        u16x8 val = *(const u16x8*)&T[seg * 128 + up * 4];
        *(u16x8*)(As + (size_t)(bt0 + seg) * OO + o0 + lane16 * 8) = val;
    }
}

// -------- stage helper for chunk_a: 32KB contiguous, pre-swizzled source ----
// 1024 threads: each lane issues 2 dma16 (seg = w*2+q, 32 segs x 1KB).
__device__ __forceinline__ void stage_a(const unsigned short* Astep,
                                        unsigned short* dstBuf, int w, int l) {
#pragma unroll
    for (int q = 0; q < 2; ++q) {
        int seg = w * 2 + q;                 // 0..31
        int du = seg * 64 + l;               // 0..2047 16B-units
        int row = du >> 4, cu = du & 15;
        int su = (du & ~15) | (cu ^ (row & 7));
        dma16(Astep + (size_t)su * 8, &dstBuf[seg * 512]);
    }
}

// per-step body (reads PTC + Abuf[KB&1], writes PTN; stage k+1; ONE barrier)
#define STEP_A(PTC, PTN, KS)                                                   \
    do {                                                                       \
        if ((KS) + 1 < Lc)                                                     \
            stage_a(AsC + (size_t)((KS) + 1) * OO,                             \
                    &AbufF[(((KS) + 1) & 1) * OO], w, l);                      \
        const unsigned short* Ac = &AbufF[((KS) & 1) * OO];                    \
        _Pragma("unroll")                                                      \
        for (int kt = 0; kt < 4; ++kt) {                                       \
            const int uoff = (((kt * 4 + lg) ^ kxor) << 3);                    \
            short8 af0 = *(const short8*)&Ac[((32 * wr + lr) << 7) | uoff];    \
            short8 af1 =                                                       \
                *(const short8*)&Ac[((32 * wr + 16 + lr) << 7) | uoff];        \
            short8 bf0 = *(const short8*)&PTC[((32 * wc + lr) << 7) | uoff];   \
            short8 bf1 =                                                       \
                *(const short8*)&PTC[((32 * wc + 16 + lr) << 7) | uoff];       \
            acc[0][0] = __builtin_amdgcn_mfma_f32_16x16x32_bf16(               \
                af0, bf0, acc[0][0], 0, 0, 0);                                 \
            acc[0][1] = __builtin_amdgcn_mfma_f32_16x16x32_bf16(               \
                af0, bf1, acc[0][1], 0, 0, 0);                                 \
            acc[1][0] = __builtin_amdgcn_mfma_f32_16x16x32_bf16(               \
                af1, bf0, acc[1][0], 0, 0, 0);                                 \
            acc[1][1] = __builtin_amdgcn_mfma_f32_16x16x32_bf16(               \
                af1, bf1, acc[1][1], 0, 0, 0);                                 \
            if (w < 8) {                                                       \
                short8 afv =                                                   \
                    *(const short8*)&Ac[((16 * w + lr) << 7) | uoff];          \
                short8 vf = *(const short8*)&PTC[(128 << 7) |                  \
                                                 ((kt * 4 + lg) << 3)];        \
                vacc = __builtin_amdgcn_mfma_f32_16x16x32_bf16(afv, vf, vacc,  \
                                                               0, 0, 0);       \
            }                                                                  \
        }                                                                      \
        _Pragma("unroll")                                                      \
        for (int tix = 0; tix < 2; ++tix)                                      \
            _Pragma("unroll")                                                  \
            for (int tjx = 0; tjx < 2; ++tjx) {                                \
                int i0 = 32 * wr + 16 * tix + 4 * lg;                          \
                int j = 32 * wc + 16 * tjx + lr;                               \
                float v0 =                                                     \
                    acc[tix][tjx][0] + ((rd[tix][tjx] == 0) ? 1.f : 0.f);      \
                float v1 =                                                     \
                    acc[tix][tjx][1] + ((rd[tix][tjx] == 1) ? 1.f : 0.f);      \
                float v2 =                                                     \
                    acc[tix][tjx][2] + ((rd[tix][tjx] == 2) ? 1.f : 0.f);      \
                float v3 =                                                     \
                    acc[tix][tjx][3] + ((rd[tix][tjx] == 3) ? 1.f : 0.f);      \
                uint2 pk;                                                      \
                pk.x = cvt_pk_bf16(v0, v1);                                    \
                pk.y = cvt_pk_bf16(v2, v3);                                    \
                int unit = (i0 >> 3) ^ (j & 7);                                \
                *(uint2*)&PTN[(j << 7) | (unit << 3) | (i0 & 7)] = pk;         \
            }                                                                  \
        if (w < 8 && lr == 0) {                                                \
            int i0 = 16 * w + 4 * lg;                                          \
            const float* bp = &BsL[(KS)][i0];                                  \
            uint2 pk;                                                          \
            vacc[0] += bp[0]; vacc[1] += bp[1];                                \
            vacc[2] += bp[2]; vacc[3] += bp[3];                                \
            pk.x = cvt_pk_bf16(vacc[0], vacc[1]);                              \
            pk.y = cvt_pk_bf16(vacc[2], vacc[3]);                              \
            *(uint2*)&PTN[(128 << 7) | i0] = pk;                               \
        }                                                                      \
        asm volatile("s_waitcnt vmcnt(0) lgkmcnt(0)" ::: "memory");            \
        __builtin_amdgcn_s_barrier();                                          \
        asm volatile("" ::: "memory");                                         \
    } while (0)

// -------- stage a: per-chunk Delta (128x128) and v via MFMA --------
// grid (NCs, Bz); 1024 thr = 16 waves (4x4); wave tile 32x32. A ring-2
// (stage k+1 during step k), Pt double-buffered => ONE barrier per step.
__global__ __launch_bounds__(1024) void k_chunk_a(
    const unsigned short* __restrict__ As, const float* __restrict__ Bs,
    float* __restrict__ Dm, float* __restrict__ Vv,
    int t0, int Lsteps, int NCs) {
    const int cs = blockIdx.x, b = blockIdx.y;
    const int tid = threadIdx.x;
    const int w = tid >> 6, l = tid & 63;
    const int lr = l & 15, lg = l >> 4;
    const int wr = w >> 2, wc = w & 3;
    int Lc = Lsteps - cs * CHUNK; if (Lc > CHUNK) Lc = CHUNK;

    __shared__ __align__(16) unsigned short AbufF[2 * OO];   // 64 KB ring-2
    __shared__ __align__(16) unsigned short PtA[129 * Hz];   // 33 KB
    __shared__ __align__(16) unsigned short PtB[129 * Hz];   // 33 KB
    __shared__ __align__(16) float BsL[CHUNK][Hz];           // 8 KB

    const unsigned short* AsC = As + (size_t)(b * NCs + cs) * CHUNK * OO;

    stage_a(AsC, &AbufF[0], w, l);                    // step 0 -> buf 0

    // PtA = [I ; v=0] (swizzled rows)
    for (int idx = tid; idx < 129 * Hz; idx += 1024) {
        int row = idx >> 7, col = idx & 127;
        unsigned short val = (row < Hz && row == col) ? (unsigned short)0x3F80
                                                      : (unsigned short)0;
        int unit = (col >> 3) ^ (row & 7);
        PtA[(row << 7) | (unit << 3) | (col & 7)] = val;
    }
    const int t0c = t0 + cs * CHUNK;
    for (int idx = tid; idx < Lc * Hz; idx += 1024) {
        int row = idx >> 7, col = idx & 127;
        BsL[row][col] = Bs[((size_t)b * NT + t0c + row) * Hz + col];
    }

    // identity: acc[tix][tjx][r] needs +1 iff r == rd[tix][tjx]
    int rd[2][2];
#pragma unroll
    for (int tix = 0; tix < 2; ++tix)
#pragma unroll
        for (int tjx = 0; tjx < 2; ++tjx)
            rd[tix][tjx] = (32 * wc + 16 * tjx + lr) -
                           (32 * wr + 16 * tix + 4 * lg);

    f32x4 acc[2][2] = {};
    f32x4 vacc = {};
    const int kxor = lr & 7;

    __syncthreads();                 // PtA + BsL + stage(0) done (vmcnt drain)

    for (int k2 = 0; k2 < CHUNK / 2; ++k2) {
        int k = 2 * k2;
        if (k >= Lc) break;
        STEP_A(PtA, PtB, k);
        if (k + 1 < Lc) STEP_A(PtB, PtA, k + 1);
    }

    // write Delta (fp32) + v to global
    const size_t ci = (size_t)b * NCs + cs;
    float* D = Dm + ci * OO;
#pragma unroll
    for (int tix = 0; tix < 2; ++tix)
#pragma unroll
        for (int tjx = 0; tjx < 2; ++tjx) {
            int i0 = 32 * wr + 16 * tix + 4 * lg;
            int j = 32 * wc + 16 * tjx + lr;
#pragma unroll
            for (int r = 0; r < 4; ++r)
                D[(size_t)(i0 + r) * Hz + j] = acc[tix][tjx][r];
        }
    if (w < 8 && lr == 0) {
        int i0 = 16 * w + 4 * lg;
        float* V = Vv + ci * Hz;
#pragma unroll
        for (int r = 0; r < 4; ++r) V[i0 + r] = vacc[r];
    }
}

// -------- stage b: sequential over chunks, y_end = y + Delta y + v --------
__global__ __launch_bounds__(1024) void k_chunk_b(
    const float* __restrict__ Dm, const float* __restrict__ Vv,
    float* __restrict__ out, int t0, int Lsteps, int NCs) {
    const int b = blockIdx.x, tid = threadIdx.x;
    const int i = tid >> 3, q = tid & 7;
    __shared__ __align__(16) float yv[2][Hz];
    __shared__ float VvL[32 * Hz];

    if (tid < Hz) yv[0][tid] = out[((size_t)b * Sz + t0) * Hz + tid];
    for (int idx = tid; idx < NCs * Hz; idx += 1024)
        VvL[idx] = Vv[(size_t)b * NCs * Hz + idx];
    __syncthreads();

    const float4* D0 = (const float4*)(Dm + (size_t)b * NCs * OO);
    const int off = i * 32 + q * 4;        // float4 index: row i, col q*16
    float4 cur[4], n1[4], n2[4];
#pragma unroll
    for (int v = 0; v < 4; ++v) cur[v] = D0[off + v];
    {
        int c1i = (NCs > 1) ? 1 : 0;
        const float4* Dn = D0 + (size_t)c1i * (OO / 4);
#pragma unroll
        for (int v = 0; v < 4; ++v) n1[v] = Dn[off + v];
    }

    for (int cs = 0; cs < NCs; ++cs) {
        int nc2 = (cs + 2 < NCs) ? cs + 2 : NCs - 1;
        const float4* Dn = D0 + (size_t)nc2 * (OO / 4);
#pragma unroll
        for (int v = 0; v < 4; ++v) n2[v] = Dn[off + v];   // stays in flight

        const int cb = cs & 1;
        const float* yp = &yv[cb][q * 16];
        float s = 0.f;
#pragma unroll
        for (int v = 0; v < 4; ++v)
            s += cur[v].x * yp[v * 4 + 0] + cur[v].y * yp[v * 4 + 1] +
                 cur[v].z * yp[v * 4 + 2] + cur[v].w * yp[v * 4 + 3];
        s += __shfl_xor(s, 1);
        s += __shfl_xor(s, 2);
        s += __shfl_xor(s, 4);

        if (q == 0) {
            float yn = yv[cb][i] + s + VvL[cs * Hz + i];
            yv[cb ^ 1][i] = yn;
            int t_end = t0 + (cs + 1) * CHUNK;
            if (t_end < Sz)
                out[((size_t)b * Sz + t_end) * Hz + i] = yn;  // boundary row
        }
        asm volatile("s_waitcnt lgkmcnt(0)" ::: "memory");
        __builtin_amdgcn_s_barrier();
        asm volatile("" ::: "memory");
#pragma unroll
        for (int v = 0; v < 4; ++v) { cur[v] = n1[v]; n1[v] = n2[v]; }
    }
}

// -------- stage c: CHUNK-step replay per chunk (interior rows) --------
__global__ __launch_bounds__(1024) void k_chunk_c(
    const unsigned short* __restrict__ As, const float* __restrict__ Bs,
    float* __restrict__ out, int t0, int Lsteps, int NCs) {
    const int cs = blockIdx.x, b = blockIdx.y;
    const int tid = threadIdx.x;
    const int i = tid >> 3, p = tid & 7;
    const int t0c = t0 + cs * CHUNK;
    int Lc = Lsteps - cs * CHUNK; if (Lc > CHUNK) Lc = CHUNK;
    __shared__ __align__(16) float y[2][Hz];

    if (tid < Hz) y[0][tid] = out[((size_t)b * Sz + t0c) * Hz + tid];
    __syncthreads();

    const unsigned short* Abp = As + (size_t)(b * NCs + cs) * CHUNK * OO +
                                i * Hz + p * 16;
    const float* Bsb = Bs + (size_t)b * NT * Hz;
    float* outb = out + (size_t)b * Sz * Hz;

    u16x8 c0 = *(const u16x8*)(Abp);
    u16x8 c1 = *(const u16x8*)(Abp + 8);
    int l1 = (Lc > 1) ? 1 : 0;
    u16x8 d0 = *(const u16x8*)(Abp + (size_t)l1 * OO);
    u16x8 d1 = *(const u16x8*)(Abp + (size_t)l1 * OO + 8);

    for (int lt = 0; lt < Lc; ++lt) {
        int ln = lt + 2; if (ln > Lc - 1) ln = Lc - 1;
        u16x8 e0 = *(const u16x8*)(Abp + (size_t)ln * OO);
        u16x8 e1 = *(const u16x8*)(Abp + (size_t)ln * OO + 8);

        const int cur = lt & 1;
        const float4* yp = (const float4*)&y[cur][p * 16];
        float4 y0v = yp[0], y1v = yp[1], y2v = yp[2], y3v = yp[3];

        float s;
        s  = bf2f(c0[0]) * y0v.x + bf2f(c0[1]) * y0v.y +
             bf2f(c0[2]) * y0v.z + bf2f(c0[3]) * y0v.w;
        s += bf2f(c0[4]) * y1v.x + bf2f(c0[5]) * y1v.y +
             bf2f(c0[6]) * y1v.z + bf2f(c0[7]) * y1v.w;
        s += bf2f(c1[0]) * y2v.x + bf2f(c1[1]) * y2v.y +
             bf2f(c1[2]) * y2v.z + bf2f(c1[3]) * y2v.w;
        s += bf2f(c1[4]) * y3v.x + bf2f(c1[5]) * y3v.y +
             bf2f(c1[6]) * y3v.z + bf2f(c1[7]) * y3v.w;
        s += __shfl_xor(s, 1);
        s += __shfl_xor(s, 2);
        s += __shfl_xor(s, 4);

        if (p == 0) {
            int t = t0c + lt;
            float st = s + Bsb[(size_t)t * Hz + i];
            float yn = y[cur][i] + st;
            y[cur ^ 1][i] = yn;
            if (((t + 1) & (CHUNK - 1)) != 0)        // boundaries: stage b
                outb[(size_t)(t + 1) * Hz + i] = yn;
        }
        c0 = d0; c1 = d1; d0 = e0; d1 = e1;
        asm volatile("s_waitcnt lgkmcnt(0)" ::: "memory");
        __builtin_amdgcn_s_barrier();
        asm volatile("" ::: "memory");
    }
}

// -------- fallback (ws tiny) --------
__global__ __launch_bounds__(1024) void k_fused(const float* __restrict__ X,
                                                const float* __restrict__ initW,
                                                const float* __restrict__ initb,
                                                const float* __restrict__ WA,
                                                const float* __restrict__ WB,
                                                float* __restrict__ out) {
    const int b = blockIdx.x, tid = threadIdx.x;
    const int i = tid >> 3, p = tid & 7;
    __shared__ float y[2][Hz];
    __shared__ float u[KK];

    if (tid < Hz) {
        float a = initb[tid];
        const float* xr = X + (size_t)b * Sz * Dz;
        const float* wr = initW + (size_t)tid * Dz;
        for (int d = 0; d < Dz; ++d) a += xr[d] * wr[d];
        y[0][tid] = a;
        out[(size_t)b * Sz * Hz + tid] = a;
    }
    __syncthreads();

    for (int t = 0; t < NT; ++t) {
        if (tid < KK)
            u[tid] = (tid == 0) ? DT
                                : X[((size_t)b * Sz + t + 1) * Dz + tid - 1] * DT;
        __syncthreads();
        const int cur = t & 1;
        float partial = 0.f;
        for (int jj = 0; jj < 16; ++jj) {
            int j = p * 16 + jj;
            const float* wr = WA + (size_t)(i * Hz + j) * KK;
            float a = 0.f;
            for (int d = 0; d < KK; ++d) a += wr[d] * u[d];
            partial += a * y[cur][j];
        }
        partial += __shfl_xor(partial, 1);
        partial += __shfl_xor(partial, 2);
        partial += __shfl_xor(partial, 4);
        if (p == 0) {
            const float* wb = WB + (size_t)i * KK;
            float bv = 0.f;
            for (int d = 0; d < KK; ++d) bv += wb[d] * u[d];
            float yn = y[cur][i] + partial + bv;
            y[cur ^ 1][i] = yn;
            out[(size_t)b * Sz * Hz + (size_t)(t + 1) * Hz + i] = yn;
        }
        __syncthreads();
    }
}

extern "C" void kernel_launch(void* const* d_in, const int* in_sizes, int n_in,
                              void* d_out, int out_size, void* d_ws,
                              size_t ws_size, hipStream_t stream) {
    const float* X = (const float*)d_in[0];
    const float* initW = (const float*)d_in[1];
    const float* initb = (const float*)d_in[2];
    const float* WA = (const float*)d_in[3];
    const float* WB = (const float*)d_in[4];
    float* out = (float*)d_out;

    // ws layout
    const size_t WH_OFF = 0;                          // 2 MB
    const size_t WL_OFF = 2097152;                    // 2 MB
    const size_t WA0_OFF = 4194304;                   // 64 KB
    const size_t XH_OFF = 4259840;                    // 512 KB (4096 x 64)
    const size_t BS_OFF = 5308416;                    // 2 MB (8*511*128 f32)
    const size_t base = 7401472;
    const size_t PER_SC = (size_t)Bz * OO * 4 +       // Dm per chunk-col
                          (size_t)Bz * Hz * 4 +       // Vv per chunk-col
                          (size_t)Bz * CHUNK * OO * 2;// As per chunk-col
    const int NC = (NT + CHUNK - 1) / CHUNK;          // 32

    long SC_max = (ws_size > base) ? (long)((ws_size - base) / PER_SC) : 0;
    if (SC_max >= 1) {
        if (SC_max > NC) SC_max = NC;
        int nS = (NC + (int)SC_max - 1) / (int)SC_max;
        int SC = (NC + nS - 1) / nS;

        unsigned short* Wh = (unsigned short*)((char*)d_ws + WH_OFF);
        unsigned short* Wl = (unsigned short*)((char*)d_ws + WL_OFF);
        float* WA0d = (float*)((char*)d_ws + WA0_OFF);
        unsigned short* Xh = (unsigned short*)((char*)d_ws + XH_OFF);
        float* Bs = (float*)((char*)d_ws + BS_OFF);
        float* Dm = (float*)((char*)d_ws + base);
        float* Vv = (float*)((char*)d_ws + base + (size_t)SC * Bz * OO * 4);
        unsigned short* As = (unsigned short*)((char*)d_ws + base +
                                               (size_t)SC * Bz * OO * 4 +
                                               (size_t)SC * Bz * Hz * 4);

        if (nS == 1) {
            // single slice: one merged prologue dispatch
            int Lsteps = NT;                          // 511
            int NCs = NC;                             // 32
            int Lpad = NCs * CHUNK;                   // 512
            int prep_blocks = (Bz * Lpad * 8) / 256;  // 1024
            k_setup<<<2560 + prep_blocks, 256, 0, stream>>>(
                X, initW, initb, WA, WB, Wh, Wl, WA0d, Bs, Xh, out, Lsteps,
                Lpad);
            k_gemm_mfma<<<dim3(128, (Bz * Lpad) / 128), 256, 0, stream>>>(
                Xh, Wh, Wl, WA0d, As);
            k_chunk_a<<<dim3(NCs, Bz), 1024, 0, stream>>>(As, Bs, Dm, Vv, 0,
                                                          Lsteps, NCs);
            k_chunk_b<<<Bz, 1024, 0, stream>>>(Dm, Vv, out, 0, Lsteps, NCs);
            k_chunk_c<<<dim3(NCs, Bz), 1024, 0, stream>>>(As, Bs, out, 0,
                                                          Lsteps, NCs);
        } else {
            k_setup_nosplice<<<2560, 256, 0, stream>>>(X, initW, initb, WA, WB,
                                                       Wh, Wl, WA0d, Bs, out);
            for (int c0 = 0; c0 < NC; c0 += SC) {
                int t0 = c0 * CHUNK;
                int Lsteps = NT - t0;
                if (Lsteps > SC * CHUNK) Lsteps = SC * CHUNK;
                int NCs = (Lsteps + CHUNK - 1) / CHUNK;
                int Lpad = NCs * CHUNK;
                k_prep<<<(Bz * Lpad * 8) / 256, 256, 0, stream>>>(X, Xh, t0,
                                                                  Lsteps, Lpad);
                k_gemm_mfma<<<dim3(128, (Bz * Lpad) / 128), 256, 0, stream>>>(
                    Xh, Wh, Wl, WA0d, As);
                k_chunk_a<<<dim3(NCs, Bz), 1024, 0, stream>>>(As, Bs, Dm, Vv,
                                                              t0, Lsteps, NCs);
                k_chunk_b<<<Bz, 1024, 0, stream>>>(Dm, Vv, out, t0, Lsteps,
                                                   NCs);
                k_chunk_c<<<dim3(NCs, Bz), 1024, 0, stream>>>(As, Bs, out, t0,
                                                              Lsteps, NCs);
            }
        }
    } else {
        k_fused<<<Bz, 1024, 0, stream>>>(X, initW, initb, WA, WB, out);
    }
}

// Round 17
// 154.264 us; speedup vs baseline: 1.4431x; 1.0029x over previous
//
#include <hip/hip_runtime.h>
#include <hip/hip_bf16.h>

// LinearCDE: y_{t+1} = y_t + A_t y_t + b_t, A_t = reshape(vf_A_W @ u_t, HxH),
// u_t = [1, X[:,t+1]] * DT.  CLIP=1e11 => tanh is identity to ~1e-10 rel.
//
// Round-17: r16 (best, 154.7us) + chunk_a final-step short-circuit: last step
// skips Pt writeback + vmcnt drain + barrier (Pt never read again; Delta/v
// come from registers; only vacc += Bs[last] kept). Everything else identical.
#define DT 0.025f
#define Bz 8
#define Sz 512
#define Dz 64
#define Hz 128
#define NT 511            // S-1 steps
#define OO (Hz * Hz)      // 16384
#define KK (Dz + 1)       // 65
#define CHUNK 16

using short8 = __attribute__((ext_vector_type(8))) short;
using f32x4  = __attribute__((ext_vector_type(4))) float;
using u16x8  = __attribute__((ext_vector_type(8))) unsigned short;
using u16x4  = __attribute__((ext_vector_type(4))) unsigned short;

__device__ __forceinline__ float bf2f(unsigned short u) {
    union { unsigned int i; float f; } v;
    v.i = ((unsigned int)u) << 16;
    return v.f;
}
__device__ __forceinline__ unsigned short f2bf(float f) {
    union { float f; unsigned int i; } v;
    v.f = f;
    unsigned int u = v.i;
    return (unsigned short)((u + 0x7FFFu + ((u >> 16) & 1u)) >> 16);  // RNE
}
// packed f32x2 -> bf16x2 (RNE), gfx950 hw cvt
__device__ __forceinline__ unsigned int cvt_pk_bf16(float lo, float hi) {
    unsigned int r;
    asm("v_cvt_pk_bf16_f32 %0, %1, %2" : "=v"(r) : "v"(lo), "v"(hi));
    return r;
}

// async 16B global -> LDS (dest: wave-uniform base + lane*16)
__device__ __forceinline__ void dma16(const void* g, void* s) {
    __builtin_amdgcn_global_load_lds(
        (const __attribute__((address_space(1))) unsigned int*)g,
        (__attribute__((address_space(3))) unsigned int*)s, 16, 0, 0);
}

// ---------------- prologue work items (device functions) ----------------
__device__ __forceinline__ void do_wsplit(int bid, int tid,
                                          const float* __restrict__ WA,
                                          unsigned short* __restrict__ Wh,
                                          unsigned short* __restrict__ Wl,
                                          float* __restrict__ WA0d) {
    int idx = bid * 256 + tid;                  // 512 blocks: 16384 o x 8 units
    int o = idx >> 3, u = idx & 7;
    const float* wr = WA + (size_t)o * KK + 1 + u * 8;
    u16x8 h = {}, lo = {};
#pragma unroll
    for (int j = 0; j < 8; ++j) {
        float v = wr[j];
        unsigned short hh = f2bf(v);
        h[j] = hh;
        lo[j] = f2bf(v - bf2f(hh));
    }
    *(u16x8*)(Wh + (size_t)o * 64 + u * 8) = h;
    *(u16x8*)(Wl + (size_t)o * 64 + u * 8) = lo;
    if (u == 0) WA0d[o] = DT * WA[(size_t)o * KK];
}

__device__ __forceinline__ void do_y0(int bid, int tid,
                                      const float* __restrict__ X,
                                      const float* __restrict__ W,
                                      const float* __restrict__ bias,
                                      float* __restrict__ out) {
    int idx = bid * 256 + tid;                  // 4 blocks
    int b = idx >> 7, h = idx & 127;
    const float* xr = X + (size_t)b * Sz * Dz;
    const float* wr = W + (size_t)h * Dz;
    float acc = bias[h];
    for (int d = 0; d < Dz; ++d) acc += xr[d] * wr[d];
    out[(size_t)b * Sz * Hz + h] = acc;
}

__device__ __forceinline__ void do_bs(int bid, int tid,
                                      const float* __restrict__ X,
                                      const float* __restrict__ WB,
                                      float* __restrict__ Bs) {
    int idx = bid * 256 + tid;                  // 2044 blocks
    int bt = idx >> 7, h = idx & 127;
    int b = bt / NT, t = bt - b * NT;
    const float* xr = X + ((size_t)b * Sz + t + 1) * Dz;
    const float* wr = WB + (size_t)h * KK;
    float acc = wr[0];
    for (int k = 0; k < Dz; ++k) acc += xr[k] * wr[1 + k];
    Bs[(size_t)bt * Hz + h] = acc * DT;
}

__device__ __forceinline__ void do_prep(int bid, int tid,
                                        const float* __restrict__ X,
                                        unsigned short* __restrict__ Xh,
                                        int t0, int Lsteps, int Lpad) {
    int idx = bid * 256 + tid;
    int m = idx >> 3, u = idx & 7;
    int b = m / Lpad, lt = m - b * Lpad;
    u16x8 h = {};
    if (lt < Lsteps) {
        const float* xr = X + ((size_t)b * Sz + t0 + lt + 1) * Dz + u * 8;
#pragma unroll
        for (int j = 0; j < 8; ++j) h[j] = f2bf(xr[j] * DT);
    }
    *(u16x8*)(Xh + (size_t)m * 64 + u * 8) = h;
}

// -------- merged prologue (single-slice fast path) --------
// blocks [0,512): wsplit | [512,516): y0 | [516,2560): bs | [2560,2560+P): prep
__global__ __launch_bounds__(256) void k_setup(
    const float* __restrict__ X, const float* __restrict__ initW,
    const float* __restrict__ initb, const float* __restrict__ WA,
    const float* __restrict__ WB, unsigned short* __restrict__ Wh,
    unsigned short* __restrict__ Wl, float* __restrict__ WA0d,
    float* __restrict__ Bs, unsigned short* __restrict__ Xh,
    float* __restrict__ out, int Lsteps, int Lpad) {
    const int bid = blockIdx.x, tid = threadIdx.x;
    if (bid < 512) {
        do_wsplit(bid, tid, WA, Wh, Wl, WA0d);
    } else if (bid < 516) {
        do_y0(bid - 512, tid, X, initW, initb, out);
    } else if (bid < 2560) {
        do_bs(bid - 516, tid, X, WB, Bs);
    } else {
        do_prep(bid - 2560, tid, X, Xh, 0, Lsteps, Lpad);
    }
}

// standalone variants for the multi-slice fallback path
__global__ __launch_bounds__(256) void k_setup_nosplice(
    const float* __restrict__ X, const float* __restrict__ initW,
    const float* __restrict__ initb, const float* __restrict__ WA,
    const float* __restrict__ WB, unsigned short* __restrict__ Wh,
    unsigned short* __restrict__ Wl, float* __restrict__ WA0d,
    float* __restrict__ Bs, float* __restrict__ out) {
    const int bid = blockIdx.x, tid = threadIdx.x;
    if (bid < 512) {
        do_wsplit(bid, tid, WA, Wh, Wl, WA0d);
    } else if (bid < 516) {
        do_y0(bid - 512, tid, X, initW, initb, out);
    } else {
        do_bs(bid - 516, tid, X, WB, Bs);
    }
}
__global__ __launch_bounds__(256) void k_prep(const float* __restrict__ X,
                                              unsigned short* __restrict__ Xh,
                                              int t0, int Lsteps, int Lpad) {
    do_prep(blockIdx.x, threadIdx.x, X, Xh, t0, Lsteps, Lpad);
}

// -------- As GEMM via MFMA, 2-term split, step-major output --------
// block 256 thr (4 waves 2x2), tile 128 m' x 128 o, K=64.
// As[m'][o] = bf16( xh*(Wh+Wl) + DT*WA[o][0] ),  m' row = (b*NCs+cs)*16 + k
__global__ __launch_bounds__(256, 3) void k_gemm_mfma(
    const unsigned short* __restrict__ Xh,
    const unsigned short* __restrict__ Wh, const unsigned short* __restrict__ Wl,
    const float* __restrict__ WA0d, unsigned short* __restrict__ As) {
    const int tid = threadIdx.x;
    const int w = tid >> 6, l = tid & 63;
    const int lr = l & 15, lg = l >> 4;
    const int wbt = w >> 1, wo = w & 1;
    const int o0 = blockIdx.x * 128;
    const int bt0 = blockIdx.y * 128;

    __shared__ __align__(16) unsigned short L[3 * 8192];  // Xh|Wh|Wl 128x64

#pragma unroll
    for (int q = 0; q < 4; ++q) {
        int seg = w * 4 + q;                 // 0..15 per buffer
        int du = seg * 64 + l;               // 0..1023 16B-units
        int row = du >> 3;
        int su = (du & ~7) | ((du & 7) ^ (row & 7));
        dma16(Xh + (size_t)bt0 * 64 + su * 8, &L[0 * 8192 + seg * 512]);
        dma16(Wh + (size_t)o0 * 64 + su * 8, &L[1 * 8192 + seg * 512]);
        dma16(Wl + (size_t)o0 * 64 + su * 8, &L[2 * 8192 + seg * 512]);
    }
    __syncthreads();   // implicit vmcnt(0): staging done

    f32x4 acc[4][4] = {};   // [oti][bti]
    const unsigned short* Xh_l = &L[0];
    const unsigned short* Wh_l = &L[8192];
    const unsigned short* Wl_l = &L[16384];

#pragma unroll
    for (int kk = 0; kk < 2; ++kk) {
        short8 xh[4], wh[4], wl[4];
#pragma unroll
        for (int t = 0; t < 4; ++t) {
            int btr = wbt * 64 + t * 16 + lr;
            int orr = wo * 64 + t * 16 + lr;
            int ux = (kk * 4 + lg) ^ (btr & 7);
            int uw = (kk * 4 + lg) ^ (orr & 7);
            xh[t] = *(const short8*)&Xh_l[btr * 64 + ux * 8];
            wh[t] = *(const short8*)&Wh_l[orr * 64 + uw * 8];
            wl[t] = *(const short8*)&Wl_l[orr * 64 + uw * 8];
        }
#pragma unroll
        for (int ot = 0; ot < 4; ++ot)
#pragma unroll
            for (int bt = 0; bt < 4; ++bt) {
                acc[ot][bt] = __builtin_amdgcn_mfma_f32_16x16x32_bf16(
                    wh[ot], xh[bt], acc[ot][bt], 0, 0, 0);
                acc[ot][bt] = __builtin_amdgcn_mfma_f32_16x16x32_bf16(
                    wl[ot], xh[bt], acc[ot][bt], 0, 0, 0);
            }
    }

    __syncthreads();                 // frag reads done; reuse L[0:16K u16] as T
    // T: 128 rows (m'_local) x 128 cols (o_local), 8B-unit XOR swizzle
    unsigned short* T = &L[0];
#pragma unroll
    for (int ot = 0; ot < 4; ++ot) {
        int obase = wo * 64 + ot * 16 + lg * 4;
        float4 wa = *(const float4*)&WA0d[o0 + obase];
#pragma unroll
        for (int bt = 0; bt < 4; ++bt) {
            int btl = wbt * 64 + bt * 16 + lr;
            u16x4 pk;
            pk[0] = f2bf(acc[ot][bt][0] + wa.x);
            pk[1] = f2bf(acc[ot][bt][1] + wa.y);
            pk[2] = f2bf(acc[ot][bt][2] + wa.z);
            pk[3] = f2bf(acc[ot][bt][3] + wa.w);
            int up = (obase >> 2) ^ ((btl & 15) << 1);
            *(u16x4*)&T[btl * 128 + up * 4] = pk;
        }
    }
    __syncthreads();
    // out-copy: per instruction, 16 lanes fully cover each 256B segment
    const int lane16 = tid & 15;
    const int segb = tid >> 4;           // 0..15
#pragma unroll
    for (int it = 0; it < 8; ++it) {
        int seg = it * 16 + segb;        // m'_local 0..127
        int up = (lane16 * 2) ^ ((seg & 15) << 1);
        u16x8 val = *(const u16x8*)&T[seg * 128 + up * 4];
        *(u16x8*)(As + (size_t)(bt0 + seg) * OO + o0 + lane16 * 8) = val;
    }
}

// -------- stage helper for chunk_a: 32KB contiguous, pre-swizzled source ----
// 1024 threads: each lane issues 2 dma16 (seg = w*2+q, 32 segs x 1KB).
__device__ __forceinline__ void stage_a(const unsigned short* Astep,
                                        unsigned short* dstBuf, int w, int l) {
#pragma unroll
    for (int q = 0; q < 2; ++q) {
        int seg = w * 2 + q;                 // 0..31
        int du = seg * 64 + l;               // 0..2047 16B-units
        int row = du >> 4, cu = du & 15;
        int su = (du & ~15) | (cu ^ (row & 7));
        dma16(Astep + (size_t)su * 8, &dstBuf[seg * 512]);
    }
}

// MFMA body shared by full and last steps (reads PTC + Abuf[KS&1])
#define MFMA_A(PTC, KS)                                                        \
    do {                                                                       \
        const unsigned short* Ac = &AbufF[((KS) & 1) * OO];                    \
        _Pragma("unroll")                                                      \
        for (int kt = 0; kt < 4; ++kt) {                                       \
            const int uoff = (((kt * 4 + lg) ^ kxor) << 3);                    \
            short8 af0 = *(const short8*)&Ac[((32 * wr + lr) << 7) | uoff];    \
            short8 af1 =                                                       \
                *(const short8*)&Ac[((32 * wr + 16 + lr) << 7) | uoff];        \
            short8 bf0 = *(const short8*)&PTC[((32 * wc + lr) << 7) | uoff];   \
            short8 bf1 =                                                       \
                *(const short8*)&PTC[((32 * wc + 16 + lr) << 7) | uoff];       \
            acc[0][0] = __builtin_amdgcn_mfma_f32_16x16x32_bf16(               \
                af0, bf0, acc[0][0], 0, 0, 0);                                 \
            acc[0][1] = __builtin_amdgcn_mfma_f32_16x16x32_bf16(               \
                af0, bf1, acc[0][1], 0, 0, 0);                                 \
            acc[1][0] = __builtin_amdgcn_mfma_f32_16x16x32_bf16(               \
                af1, bf0, acc[1][0], 0, 0, 0);                                 \
            acc[1][1] = __builtin_amdgcn_mfma_f32_16x16x32_bf16(               \
                af1, bf1, acc[1][1], 0, 0, 0);                                 \
            if (w < 8) {                                                       \
                short8 afv =                                                   \
                    *(const short8*)&Ac[((16 * w + lr) << 7) | uoff];          \
                short8 vf = *(const short8*)&PTC[(128 << 7) |                  \
                                                 ((kt * 4 + lg) << 3)];        \
                vacc = __builtin_amdgcn_mfma_f32_16x16x32_bf16(afv, vf, vacc,  \
                                                               0, 0, 0);       \
            }                                                                  \
        }                                                                      \
    } while (0)

// full step: MFMA + stage(k+1) + Pt writeback + single barrier
#define STEP_A(PTC, PTN, KS)                                                   \
    do {                                                                       \
        if ((KS) + 1 < Lc)                                                     \
            stage_a(AsC + (size_t)((KS) + 1) * OO,                             \
                    &AbufF[(((KS) + 1) & 1) * OO], w, l);                      \
        MFMA_A(PTC, KS);                                                       \
        _Pragma("unroll")                                                      \
        for (int tix = 0; tix < 2; ++tix)                                      \
            _Pragma("unroll")                                                  \
            for (int tjx = 0; tjx < 2; ++tjx) {                                \
                int i0 = 32 * wr + 16 * tix + 4 * lg;                          \
                int j = 32 * wc + 16 * tjx + lr;                               \
                float v0 =                                                     \
                    acc[tix][tjx][0] + ((rd[tix][tjx] == 0) ? 1.f : 0.f);      \
                float v1 =                                                     \
                    acc[tix][tjx][1] + ((rd[tix][tjx] == 1) ? 1.f : 0.f);      \
                float v2 =                                                     \
                    acc[tix][tjx][2] + ((rd[tix][tjx] == 2) ? 1.f : 0.f);      \
                float v3 =                                                     \
                    acc[tix][tjx][3] + ((rd[tix][tjx] == 3) ? 1.f : 0.f);      \
                uint2 pk;                                                      \
                pk.x = cvt_pk_bf16(v0, v1);                                    \
                pk.y = cvt_pk_bf16(v2, v3);                                    \
                int unit = (i0 >> 3) ^ (j & 7);                                \
                *(uint2*)&PTN[(j << 7) | (unit << 3) | (i0 & 7)] = pk;         \
            }                                                                  \
        if (w < 8 && lr == 0) {                                                \
            int i0 = 16 * w + 4 * lg;                                          \
            const float* bp = &BsL[(KS)][i0];                                  \
            uint2 pk;                                                          \
            vacc[0] += bp[0]; vacc[1] += bp[1];                                \
            vacc[2] += bp[2]; vacc[3] += bp[3];                                \
            pk.x = cvt_pk_bf16(vacc[0], vacc[1]);                              \
            pk.y = cvt_pk_bf16(vacc[2], vacc[3]);                              \
            *(uint2*)&PTN[(128 << 7) | i0] = pk;                               \
        }                                                                      \
        asm volatile("s_waitcnt vmcnt(0) lgkmcnt(0)" ::: "memory");            \
        __builtin_amdgcn_s_barrier();                                          \
        asm volatile("" ::: "memory");                                         \
    } while (0)

// last step: MFMA only; results stay in registers (no writeback, no barrier)
#define STEP_LAST(PTC, KS)                                                     \
    do {                                                                       \
        MFMA_A(PTC, KS);                                                       \
        if (w < 8 && lr == 0) {                                                \
            int i0 = 16 * w + 4 * lg;                                          \
            const float* bp = &BsL[(KS)][i0];                                  \
            vacc[0] += bp[0]; vacc[1] += bp[1];                                \
            vacc[2] += bp[2]; vacc[3] += bp[3];                                \
        }                                                                      \
    } while (0)

// -------- stage a: per-chunk Delta (128x128) and v via MFMA --------
// grid (NCs, Bz); 1024 thr = 16 waves (4x4); wave tile 32x32. A ring-2
// (stage k+1 during step k), Pt double-buffered => ONE barrier per step;
// final step short-circuits (register-only epilogue).
__global__ __launch_bounds__(1024) void k_chunk_a(
    const unsigned short* __restrict__ As, const float* __restrict__ Bs,
    float* __restrict__ Dm, float* __restrict__ Vv,
    int t0, int Lsteps, int NCs) {
    const int cs = blockIdx.x, b = blockIdx.y;
    const int tid = threadIdx.x;
    const int w = tid >> 6, l = tid & 63;
    const int lr = l & 15, lg = l >> 4;
    const int wr = w >> 2, wc = w & 3;
    int Lc = Lsteps - cs * CHUNK; if (Lc > CHUNK) Lc = CHUNK;

    __shared__ __align__(16) unsigned short AbufF[2 * OO];   // 64 KB ring-2
    __shared__ __align__(16) unsigned short PtA[129 * Hz];   // 33 KB
    __shared__ __align__(16) unsigned short PtB[129 * Hz];   // 33 KB
    __shared__ __align__(16) float BsL[CHUNK][Hz];           // 8 KB

    const unsigned short* AsC = As + (size_t)(b * NCs + cs) * CHUNK * OO;

    stage_a(AsC, &AbufF[0], w, l);                    // step 0 -> buf 0

    // PtA = [I ; v=0] (swizzled rows)
    for (int idx = tid; idx < 129 * Hz; idx += 1024) {
        int row = idx >> 7, col = idx & 127;
        unsigned short val = (row < Hz && row == col) ? (unsigned short)0x3F80
                                                      : (unsigned short)0;
        int unit = (col >> 3) ^ (row & 7);
        PtA[(row << 7) | (unit << 3) | (col & 7)] = val;
    }
    const int t0c = t0 + cs * CHUNK;
    for (int idx = tid; idx < Lc * Hz; idx += 1024) {
        int row = idx >> 7, col = idx & 127;
        BsL[row][col] = Bs[((size_t)b * NT + t0c + row) * Hz + col];
    }

    // identity: acc[tix][tjx][r] needs +1 iff r == rd[tix][tjx]
    int rd[2][2];
#pragma unroll
    for (int tix = 0; tix < 2; ++tix)
#pragma unroll
        for (int tjx = 0; tjx < 2; ++tjx)
            rd[tix][tjx] = (32 * wc + 16 * tjx + lr) -
                           (32 * wr + 16 * tix + 4 * lg);

    f32x4 acc[2][2] = {};
    f32x4 vacc = {};
    const int kxor = lr & 7;

    __syncthreads();                 // PtA + BsL + stage(0) done (vmcnt drain)

    const int kfull = Lc - 1;        // steps [0, kfull) full; step kfull last
    for (int k2 = 0;; ++k2) {
        int k = 2 * k2;
        if (k >= kfull) break;
        STEP_A(PtA, PtB, k);
        if (k + 1 >= kfull) break;
        STEP_A(PtB, PtA, k + 1);
    }
    if (kfull & 1) STEP_LAST(PtB, kfull);
    else          STEP_LAST(PtA, kfull);

    // write Delta (fp32) + v to global (from registers)
    const size_t ci = (size_t)b * NCs + cs;
    float* D = Dm + ci * OO;
#pragma unroll
    for (int tix = 0; tix < 2; ++tix)
#pragma unroll
        for (int tjx = 0; tjx < 2; ++tjx) {
            int i0 = 32 * wr + 16 * tix + 4 * lg;
            int j = 32 * wc + 16 * tjx + lr;
#pragma unroll
            for (int r = 0; r < 4; ++r)
                D[(size_t)(i0 + r) * Hz + j] = acc[tix][tjx][r];
        }
    if (w < 8 && lr == 0) {
        int i0 = 16 * w + 4 * lg;
        float* V = Vv + ci * Hz;
#pragma unroll
        for (int r = 0; r < 4; ++r) V[i0 + r] = vacc[r];
    }
}

// -------- stage b: sequential over chunks, y_end = y + Delta y + v --------
__global__ __launch_bounds__(1024) void k_chunk_b(
    const float* __restrict__ Dm, const float* __restrict__ Vv,
    float* __restrict__ out, int t0, int Lsteps, int NCs) {
    const int b = blockIdx.x, tid = threadIdx.x;
    const int i = tid >> 3, q = tid & 7;
    __shared__ __align__(16) float yv[2][Hz];
    __shared__ float VvL[32 * Hz];

    if (tid < Hz) yv[0][tid] = out[((size_t)b * Sz + t0) * Hz + tid];
    for (int idx = tid; idx < NCs * Hz; idx += 1024)
        VvL[idx] = Vv[(size_t)b * NCs * Hz + idx];
    __syncthreads();

    const float4* D0 = (const float4*)(Dm + (size_t)b * NCs * OO);
    const int off = i * 32 + q * 4;        // float4 index: row i, col q*16
    float4 cur[4], n1[4], n2[4];
#pragma unroll
    for (int v = 0; v < 4; ++v) cur[v] = D0[off + v];
    {
        int c1i = (NCs > 1) ? 1 : 0;
        const float4* Dn = D0 + (size_t)c1i * (OO / 4);
#pragma unroll
        for (int v = 0; v < 4; ++v) n1[v] = Dn[off + v];
    }

    for (int cs = 0; cs < NCs; ++cs) {
        int nc2 = (cs + 2 < NCs) ? cs + 2 : NCs - 1;
        const float4* Dn = D0 + (size_t)nc2 * (OO / 4);
#pragma unroll
        for (int v = 0; v < 4; ++v) n2[v] = Dn[off + v];   // stays in flight

        const int cb = cs & 1;
        const float* yp = &yv[cb][q * 16];
        float s = 0.f;
#pragma unroll
        for (int v = 0; v < 4; ++v)
            s += cur[v].x * yp[v * 4 + 0] + cur[v].y * yp[v * 4 + 1] +
                 cur[v].z * yp[v * 4 + 2] + cur[v].w * yp[v * 4 + 3];
        s += __shfl_xor(s, 1);
        s += __shfl_xor(s, 2);
        s += __shfl_xor(s, 4);

        if (q == 0) {
            float yn = yv[cb][i] + s + VvL[cs * Hz + i];
            yv[cb ^ 1][i] = yn;
            int t_end = t0 + (cs + 1) * CHUNK;
            if (t_end < Sz)
                out[((size_t)b * Sz + t_end) * Hz + i] = yn;  // boundary row
        }
        asm volatile("s_waitcnt lgkmcnt(0)" ::: "memory");
        __builtin_amdgcn_s_barrier();
        asm volatile("" ::: "memory");
#pragma unroll
        for (int v = 0; v < 4; ++v) { cur[v] = n1[v]; n1[v] = n2[v]; }
    }
}

// -------- stage c: CHUNK-step replay per chunk (interior rows) --------
__global__ __launch_bounds__(1024) void k_chunk_c(
    const unsigned short* __restrict__ As, const float* __restrict__ Bs,
    float* __restrict__ out, int t0, int Lsteps, int NCs) {
    const int cs = blockIdx.x, b = blockIdx.y;
    const int tid = threadIdx.x;
    const int i = tid >> 3, p = tid & 7;
    const int t0c = t0 + cs * CHUNK;
    int Lc = Lsteps - cs * CHUNK; if (Lc > CHUNK) Lc = CHUNK;
    __shared__ __align__(16) float y[2][Hz];

    if (tid < Hz) y[0][tid] = out[((size_t)b * Sz + t0c) * Hz + tid];
    __syncthreads();

    const unsigned short* Abp = As + (size_t)(b * NCs + cs) * CHUNK * OO +
                                i * Hz + p * 16;
    const float* Bsb = Bs + (size_t)b * NT * Hz;
    float* outb = out + (size_t)b * Sz * Hz;

    u16x8 c0 = *(const u16x8*)(Abp);
    u16x8 c1 = *(const u16x8*)(Abp + 8);
    int l1 = (Lc > 1) ? 1 : 0;
    u16x8 d0 = *(const u16x8*)(Abp + (size_t)l1 * OO);
    u16x8 d1 = *(const u16x8*)(Abp + (size_t)l1 * OO + 8);

    for (int lt = 0; lt < Lc; ++lt) {
        int ln = lt + 2; if (ln > Lc - 1) ln = Lc - 1;
        u16x8 e0 = *(const u16x8*)(Abp + (size_t)ln * OO);
        u16x8 e1 = *(const u16x8*)(Abp + (size_t)ln * OO + 8);

        const int cur = lt & 1;
        const float4* yp = (const float4*)&y[cur][p * 16];
        float4 y0v = yp[0], y1v = yp[1], y2v = yp[2], y3v = yp[3];

        float s;
        s  = bf2f(c0[0]) * y0v.x + bf2f(c0[1]) * y0v.y +
             bf2f(c0[2]) * y0v.z + bf2f(c0[3]) * y0v.w;
        s += bf2f(c0[4]) * y1v.x + bf2f(c0[5]) * y1v.y +
             bf2f(c0[6]) * y1v.z + bf2f(c0[7]) * y1v.w;
        s += bf2f(c1[0]) * y2v.x + bf2f(c1[1]) * y2v.y +
             bf2f(c1[2]) * y2v.z + bf2f(c1[3]) * y2v.w;
        s += bf2f(c1[4]) * y3v.x + bf2f(c1[5]) * y3v.y +
             bf2f(c1[6]) * y3v.z + bf2f(c1[7]) * y3v.w;
        s += __shfl_xor(s, 1);
        s += __shfl_xor(s, 2);
        s += __shfl_xor(s, 4);

        if (p == 0) {
            int t = t0c + lt;
            float st = s + Bsb[(size_t)t * Hz + i];
            float yn = y[cur][i] + st;
            y[cur ^ 1][i] = yn;
            if (((t + 1) & (CHUNK - 1)) != 0)        // boundaries: stage b
                outb[(size_t)(t + 1) * Hz + i] = yn;
        }
        c0 = d0; c1 = d1; d0 = e0; d1 = e1;
        asm volatile("s_waitcnt lgkmcnt(0)" ::: "memory");
        __builtin_amdgcn_s_barrier();
        asm volatile("" ::: "memory");
    }
}

// -------- fallback (ws tiny) --------
__global__ __launch_bounds__(1024) void k_fused(const float* __restrict__ X,
                                                const float* __restrict__ initW,
                                                const float* __restrict__ initb,
                                                const float* __restrict__ WA,
                                                const float* __restrict__ WB,
                                                float* __restrict__ out) {
    const int b = blockIdx.x, tid = threadIdx.x;
    const int i = tid >> 3, p = tid & 7;
    __shared__ float y[2][Hz];
    __shared__ float u[KK];

    if (tid < Hz) {
        float a = initb[tid];
        const float* xr = X + (size_t)b * Sz * Dz;
        const float* wr = initW + (size_t)tid * Dz;
        for (int d = 0; d < Dz; ++d) a += xr[d] * wr[d];
        y[0][tid] = a;
        out[(size_t)b * Sz * Hz + tid] = a;
    }
    __syncthreads();

    for (int t = 0; t < NT; ++t) {
        if (tid < KK)
            u[tid] = (tid == 0) ? DT
                                : X[((size_t)b * Sz + t + 1) * Dz + tid - 1] * DT;
        __syncthreads();
        const int cur = t & 1;
        float partial = 0.f;
        for (int jj = 0; jj < 16; ++jj) {
            int j = p * 16 + jj;
            const float* wr = WA + (size_t)(i * Hz + j) * KK;
            float a = 0.f;
            for (int d = 0; d < KK; ++d) a += wr[d] * u[d];
            partial += a * y[cur][j];
        }
        partial += __shfl_xor(partial, 1);
        partial += __shfl_xor(partial, 2);
        partial += __shfl_xor(partial, 4);
        if (p == 0) {
            const float* wb = WB + (size_t)i * KK;
            float bv = 0.f;
            for (int d = 0; d < KK; ++d) bv += wb[d] * u[d];
            float yn = y[cur][i] + partial + bv;
            y[cur ^ 1][i] = yn;
            out[(size_t)b * Sz * Hz + (size_t)(t + 1) * Hz + i] = yn;
        }
        __syncthreads();
    }
}

extern "C" void kernel_launch(void* const* d_in, const int* in_sizes, int n_in,
                              void* d_out, int out_size, void* d_ws,
                              size_t ws_size, hipStream_t stream) {
    const float* X = (const float*)d_in[0];
    const float* initW = (const float*)d_in[1];
    const float* initb = (const float*)d_in[2];
    const float* WA = (const float*)d_in[3];
    const float* WB = (const float*)d_in[4];
    float* out = (float*)d_out;

    // ws layout
    const size_t WH_OFF = 0;                          // 2 MB
    const size_t WL_OFF = 2097152;                    // 2 MB
    const size_t WA0_OFF = 4194304;                   // 64 KB
    const size_t XH_OFF = 4259840;                    // 512 KB (4096 x 64)
    const size_t BS_OFF = 5308416;                    // 2 MB (8*511*128 f32)
    const size_t base = 7401472;
    const size_t PER_SC = (size_t)Bz * OO * 4 +       // Dm per chunk-col
                          (size_t)Bz * Hz * 4 +       // Vv per chunk-col
                          (size_t)Bz * CHUNK * OO * 2;// As per chunk-col
    const int NC = (NT + CHUNK - 1) / CHUNK;          // 32

    long SC_max = (ws_size > base) ? (long)((ws_size - base) / PER_SC) : 0;
    if (SC_max >= 1) {
        if (SC_max > NC) SC_max = NC;
        int nS = (NC + (int)SC_max - 1) / (int)SC_max;
        int SC = (NC + nS - 1) / nS;

        unsigned short* Wh = (unsigned short*)((char*)d_ws + WH_OFF);
        unsigned short* Wl = (unsigned short*)((char*)d_ws + WL_OFF);
        float* WA0d = (float*)((char*)d_ws + WA0_OFF);
        unsigned short* Xh = (unsigned short*)((char*)d_ws + XH_OFF);
        float* Bs = (float*)((char*)d_ws + BS_OFF);
        float* Dm = (float*)((char*)d_ws + base);
        float* Vv = (float*)((char*)d_ws + base + (size_t)SC * Bz * OO * 4);
        unsigned short* As = (unsigned short*)((char*)d_ws + base +
                                               (size_t)SC * Bz * OO * 4 +
                                               (size_t)SC * Bz * Hz * 4);

        if (nS == 1) {
            // single slice: one merged prologue dispatch
            int Lsteps = NT;                          // 511
            int NCs = NC;                             // 32
            int Lpad = NCs * CHUNK;                   // 512
            int prep_blocks = (Bz * Lpad * 8) / 256;  // 1024
            k_setup<<<2560 + prep_blocks, 256, 0, stream>>>(
                X, initW, initb, WA, WB, Wh, Wl, WA0d, Bs, Xh, out, Lsteps,
                Lpad);
            k_gemm_mfma<<<dim3(128, (Bz * Lpad) / 128), 256, 0, stream>>>(
                Xh, Wh, Wl, WA0d, As);
            k_chunk_a<<<dim3(NCs, Bz), 1024, 0, stream>>>(As, Bs, Dm, Vv, 0,
                                                          Lsteps, NCs);
            k_chunk_b<<<Bz, 1024, 0, stream>>>(Dm, Vv, out, 0, Lsteps, NCs);
            k_chunk_c<<<dim3(NCs, Bz), 1024, 0, stream>>>(As, Bs, out, 0,
                                                          Lsteps, NCs);
        } else {
            k_setup_nosplice<<<2560, 256, 0, stream>>>(X, initW, initb, WA, WB,
                                                       Wh, Wl, WA0d, Bs, out);
            for (int c0 = 0; c0 < NC; c0 += SC) {
                int t0 = c0 * CHUNK;
                int Lsteps = NT - t0;
                if (Lsteps > SC * CHUNK) Lsteps = SC * CHUNK;
                int NCs = (Lsteps + CHUNK - 1) / CHUNK;
                int Lpad = NCs * CHUNK;
                k_prep<<<(Bz * Lpad * 8) / 256, 256, 0, stream>>>(X, Xh, t0,
                                                                  Lsteps, Lpad);
                k_gemm_mfma<<<dim3(128, (Bz * Lpad) / 128), 256, 0, stream>>>(
                    Xh, Wh, Wl, WA0d, As);
                k_chunk_a<<<dim3(NCs, Bz), 1024, 0, stream>>>(As, Bs, Dm, Vv,
                                                              t0, Lsteps, NCs);
                k_chunk_b<<<Bz, 1024, 0, stream>>>(Dm, Vv, out, t0, Lsteps,
                                                   NCs);
                k_chunk_c<<<dim3(NCs, Bz), 1024, 0, stream>>>(As, Bs, out, t0,
                                                              Lsteps, NCs);
            }
        }
    } else {
        k_fused<<<Bz, 1024, 0, stream>>>(X, initW, initb, WA, WB, out);
    }
}